// Round 1
// baseline (2432.966 us; speedup 1.0000x reference)
//
#include <hip/hip_runtime.h>

#define D 128
static constexpr float BN_EPS = 1e-5f;

// ---------------------------------------------------------------------------
// Edge scatter-add: x[dst[e]] += h_src[src[e]].  32 threads per edge, each
// thread handles 4 consecutive features (float4 gather, 4 f32 atomics).
// ---------------------------------------------------------------------------
__global__ void scatter_add_kernel(const float* __restrict__ hsrc,
                                   const int* __restrict__ src,
                                   const int* __restrict__ dst,
                                   float* __restrict__ x, int E)
{
    long long gid = (long long)blockIdx.x * blockDim.x + threadIdx.x;
    int e = (int)(gid >> 5);
    if (e >= E) return;
    int f = ((int)gid & 31) << 2;
    int s = src[e], d = dst[e];
    const float4 v = *reinterpret_cast<const float4*>(hsrc + (size_t)s * D + f);
    float* xp = x + (size_t)d * D + f;
    atomicAdd(xp + 0, v.x);
    atomicAdd(xp + 1, v.y);
    atomicAdd(xp + 2, v.z);
    atomicAdd(xp + 3, v.w);
}

// ---------------------------------------------------------------------------
// Y = X @ W  (X: [N][128], W: [128][128]); optionally applies BN+ReLU to X on
// load (scale/bias per column). Fused epilogue accumulates per-column sum and
// sum-of-squares of Y into osum/osq (for the next BN).
// Tile: 32 rows x 128 cols per block of 256 threads; thread = 4x4 outputs.
// LDS: W full (64KB) + X tile (16KB) = 80KB -> 2 blocks/CU.
// ---------------------------------------------------------------------------
template <bool BN_IN>
__global__ __launch_bounds__(256, 2) void gemm_stats_kernel(
    const float* __restrict__ X, const float* __restrict__ W,
    const float* __restrict__ sc, const float* __restrict__ bi,
    float* __restrict__ Y, float* __restrict__ osum, float* __restrict__ osq,
    int N)
{
    __shared__ float Ws[D * D];   // 64 KB
    __shared__ float Xs[32 * D];  // 16 KB
    const int t = threadIdx.x;
    const int row0 = blockIdx.x * 32;

    // Load W (whole 128x128) into LDS, coalesced float4.
    for (int i = t * 4; i < D * D; i += 256 * 4)
        *reinterpret_cast<float4*>(&Ws[i]) =
            *reinterpret_cast<const float4*>(&W[i]);

    // Load X tile (optionally BN+ReLU on the fly). Pad rows -> 0 pre-BN.
    for (int i = t * 4; i < 32 * D; i += 256 * 4) {
        int r = i >> 7, c = i & (D - 1);
        float4 v = make_float4(0.f, 0.f, 0.f, 0.f);
        if (row0 + r < N)
            v = *reinterpret_cast<const float4*>(&X[(size_t)(row0 + r) * D + c]);
        if (BN_IN) {
            float4 s4 = *reinterpret_cast<const float4*>(&sc[c]);
            float4 b4 = *reinterpret_cast<const float4*>(&bi[c]);
            v.x = fmaxf(fmaf(v.x, s4.x, b4.x), 0.f);
            v.y = fmaxf(fmaf(v.y, s4.y, b4.y), 0.f);
            v.z = fmaxf(fmaf(v.z, s4.z, b4.z), 0.f);
            v.w = fmaxf(fmaf(v.w, s4.w, b4.w), 0.f);
        }
        *reinterpret_cast<float4*>(&Xs[i]) = v;
    }
    __syncthreads();

    const int tx = t & 31;       // 0..31 -> column group
    const int ty = t >> 5;       // 0..7  -> row group
    const int c0 = tx * 4;
    const int r0 = ty * 4;

    float acc[4][4];
#pragma unroll
    for (int r = 0; r < 4; ++r)
#pragma unroll
        for (int j = 0; j < 4; ++j) acc[r][j] = 0.f;

    for (int k = 0; k < D; k += 4) {
        float w[4][4];
#pragma unroll
        for (int kk = 0; kk < 4; ++kk) {
            float4 w4 = *reinterpret_cast<const float4*>(&Ws[(k + kk) * D + c0]);
            w[kk][0] = w4.x; w[kk][1] = w4.y; w[kk][2] = w4.z; w[kk][3] = w4.w;
        }
#pragma unroll
        for (int r = 0; r < 4; ++r) {
            float4 x4 = *reinterpret_cast<const float4*>(&Xs[(r0 + r) * D + k]);
            float xv[4] = {x4.x, x4.y, x4.z, x4.w};
#pragma unroll
            for (int kk = 0; kk < 4; ++kk)
#pragma unroll
                for (int j = 0; j < 4; ++j)
                    acc[r][j] = fmaf(xv[kk], w[kk][j], acc[r][j]);
        }
    }

    // Write Y (raw, pre-BN).
#pragma unroll
    for (int r = 0; r < 4; ++r) {
        int row = row0 + r0 + r;
        if (row < N)
            *reinterpret_cast<float4*>(&Y[(size_t)row * D + c0]) =
                make_float4(acc[r][0], acc[r][1], acc[r][2], acc[r][3]);
    }

    // Column stats: reduce over block rows in LDS, one atomic per column.
    __syncthreads();  // done reading Xs; reuse as scratch
    float* s_sum = Xs;            // [8][D]
    float* s_sq  = Xs + 8 * D;    // [8][D]
    float ps[4] = {0.f, 0.f, 0.f, 0.f}, pq[4] = {0.f, 0.f, 0.f, 0.f};
#pragma unroll
    for (int r = 0; r < 4; ++r) {
        if (row0 + r0 + r < N) {
#pragma unroll
            for (int j = 0; j < 4; ++j) {
                ps[j] += acc[r][j];
                pq[j] += acc[r][j] * acc[r][j];
            }
        }
    }
#pragma unroll
    for (int j = 0; j < 4; ++j) {
        s_sum[ty * D + c0 + j] = ps[j];
        s_sq[ty * D + c0 + j]  = pq[j];
    }
    __syncthreads();
    if (t < D) {
        float a = 0.f, b = 0.f;
#pragma unroll
        for (int g = 0; g < 8; ++g) {
            a += s_sum[g * D + t];
            b += s_sq[g * D + t];
        }
        atomicAdd(&osum[t], a);
        atomicAdd(&osq[t], b);
    }
}

// ---------------------------------------------------------------------------
// mean/var -> fused scale/bias:  y_bn = y*scale + bias
// ---------------------------------------------------------------------------
__global__ void bn_finalize_kernel(const float* __restrict__ sum,
                                   const float* __restrict__ sq,
                                   const float* __restrict__ g,
                                   const float* __restrict__ b,
                                   float* __restrict__ sc,
                                   float* __restrict__ bi, int N)
{
    int c = threadIdx.x;
    float inv_n = 1.f / (float)N;
    float mean = sum[c] * inv_n;
    float var = fmaxf(sq[c] * inv_n - mean * mean, 0.f);
    float s = g[c] * rsqrtf(var + BN_EPS);
    sc[c] = s;
    bi[c] = b[c] - mean * s;
}

// ---------------------------------------------------------------------------
// out = relu(z*scale + bias), vectorized float4.
// ---------------------------------------------------------------------------
__global__ void bn_relu_out_kernel(const float* __restrict__ Z,
                                   const float* __restrict__ sc,
                                   const float* __restrict__ bi,
                                   float* __restrict__ out, int n4)
{
    for (int i = blockIdx.x * blockDim.x + threadIdx.x; i < n4;
         i += gridDim.x * blockDim.x) {
        float4 v = reinterpret_cast<const float4*>(Z)[i];
        int c = (i * 4) & (D - 1);
        float4 s4 = *reinterpret_cast<const float4*>(&sc[c]);
        float4 b4 = *reinterpret_cast<const float4*>(&bi[c]);
        v.x = fmaxf(fmaf(v.x, s4.x, b4.x), 0.f);
        v.y = fmaxf(fmaf(v.y, s4.y, b4.y), 0.f);
        v.z = fmaxf(fmaf(v.z, s4.z, b4.z), 0.f);
        v.w = fmaxf(fmaf(v.w, s4.w, b4.w), 0.f);
        reinterpret_cast<float4*>(out)[i] = v;
    }
}

// ---------------------------------------------------------------------------
extern "C" void kernel_launch(void* const* d_in, const int* in_sizes, int n_in,
                              void* d_out, int out_size, void* d_ws, size_t ws_size,
                              hipStream_t stream)
{
    const float* h_user   = (const float*)d_in[0];
    const float* h_item   = (const float*)d_in[1];
    const int* src_rates  = (const int*)d_in[2];
    const int* dst_rates  = (const int*)d_in[3];
    const int* src_rev    = (const int*)d_in[4];
    const int* dst_rev    = (const int*)d_in[5];
    const float* W1_rates = (const float*)d_in[6];
    const float* W2_rates = (const float*)d_in[7];
    const float* g1_rates = (const float*)d_in[8];
    const float* b1_rates = (const float*)d_in[9];
    const float* g2_rates = (const float*)d_in[10];
    const float* b2_rates = (const float*)d_in[11];
    const float* W1_rev   = (const float*)d_in[12];
    const float* W2_rev   = (const float*)d_in[13];
    const float* g1_rev   = (const float*)d_in[14];
    const float* b1_rev   = (const float*)d_in[15];
    const float* g2_rev   = (const float*)d_in[16];
    const float* b2_rev   = (const float*)d_in[17];

    const int n_user = in_sizes[0] / D;
    const int n_item = in_sizes[1] / D;
    const int E1 = in_sizes[2];
    const int E2 = in_sizes[4];
    const int n_max = n_user > n_item ? n_user : n_item;

    // Workspace layout: bufA | bufB | stats (2 relations x 8 arrays of D)
    float* bufA = (float*)d_ws;
    size_t buf_elems = (size_t)n_max * D;
    float* bufB = bufA + buf_elems;
    float* stats = bufB + buf_elems;

    hipMemsetAsync(stats, 0, 16 * D * sizeof(float), stream);

    float* out_user = (float*)d_out;
    float* out_item = out_user + (size_t)n_user * D;

    auto run_rel = [&](const float* hsrc, const float* hdst, const int* src,
                       const int* dst, int E, int Ndst, const float* W1,
                       const float* W2, const float* g1, const float* b1,
                       const float* g2, const float* b2, float* out, float* st) {
        // x = h_dst  (self feature)
        hipMemcpyAsync(bufA, hdst, (size_t)Ndst * D * sizeof(float),
                       hipMemcpyDeviceToDevice, stream);
        // x += segment_sum(h_src[src], dst)
        long long nthreads = (long long)E * 32;
        int sblocks = (int)((nthreads + 255) / 256);
        scatter_add_kernel<<<sblocks, 256, 0, stream>>>(hsrc, src, dst, bufA, E);

        float* sum1 = st;         float* sq1 = st + D;
        float* sc1  = st + 2 * D; float* bi1 = st + 3 * D;
        float* sum2 = st + 4 * D; float* sq2 = st + 5 * D;
        float* sc2  = st + 6 * D; float* bi2 = st + 7 * D;

        int gblocks = (Ndst + 31) / 32;
        // y = x @ W1 (+ column stats of y)
        gemm_stats_kernel<false><<<gblocks, 256, 0, stream>>>(
            bufA, W1, nullptr, nullptr, bufB, sum1, sq1, Ndst);
        bn_finalize_kernel<<<1, D, 0, stream>>>(sum1, sq1, g1, b1, sc1, bi1, Ndst);
        // z = relu(bn(y)) @ W2 (+ column stats of z)
        gemm_stats_kernel<true><<<gblocks, 256, 0, stream>>>(
            bufB, W2, sc1, bi1, bufA, sum2, sq2, Ndst);
        bn_finalize_kernel<<<1, D, 0, stream>>>(sum2, sq2, g2, b2, sc2, bi2, Ndst);
        // out = relu(bn(z))
        int n4 = (int)((size_t)Ndst * D / 4);
        int oblocks = (n4 + 255) / 256;
        if (oblocks > 2048) oblocks = 2048;
        bn_relu_out_kernel<<<oblocks, 256, 0, stream>>>(bufA, sc2, bi2, out, n4);
    };

    // relation 'rates': user -> item  => out_item
    run_rel(h_user, h_item, src_rates, dst_rates, E1, n_item,
            W1_rates, W2_rates, g1_rates, b1_rates, g2_rates, b2_rates,
            out_item, stats);
    // relation 'rated_by': item -> user => out_user
    run_rel(h_item, h_user, src_rev, dst_rev, E2, n_user,
            W1_rev, W2_rev, g1_rev, b1_rev, g2_rev, b2_rev,
            out_user, stats + 8 * D);
}

// Round 2
// 655.167 us; speedup vs baseline: 3.7135x; 3.7135x over previous
//
#include <hip/hip_runtime.h>

#define D 128
static constexpr float BN_EPS = 1e-5f;

// ---------------------------------------------------------------------------
// CSR build step 1: histogram of dst.
// ---------------------------------------------------------------------------
__global__ void hist_kernel(const int* __restrict__ dst, int* __restrict__ counts,
                            int E)
{
    int e = blockIdx.x * blockDim.x + threadIdx.x;
    if (e < E) atomicAdd(&counts[dst[e]], 1);
}

// ---------------------------------------------------------------------------
// CSR build step 2: exclusive prefix sum of counts -> offsets[N+1].
// Single block, 1024 threads, chunked serial + Hillis-Steele over partials.
// ---------------------------------------------------------------------------
__global__ __launch_bounds__(1024) void scan_kernel(const int* __restrict__ counts,
                                                    int* __restrict__ offsets, int N)
{
    __shared__ int part[1024];
    const int t = threadIdx.x;
    const int chunk = (N + 1023) / 1024;
    const int lo = t * chunk;
    const int hi = min(lo + chunk, N);
    int s = 0;
    for (int i = lo; i < hi; ++i) s += counts[i];
    part[t] = s;
    __syncthreads();
    for (int off = 1; off < 1024; off <<= 1) {
        int tmp = (t >= off) ? part[t - off] : 0;
        __syncthreads();
        part[t] += tmp;
        __syncthreads();
    }
    int excl = part[t] - s;  // exclusive sum of this thread's chunk start
    for (int i = lo; i < hi; ++i) {
        offsets[i] = excl;
        excl += counts[i];
    }
    if (t == 1023) offsets[N] = part[1023];
}

// ---------------------------------------------------------------------------
// CSR build step 3: perm[offsets[d] + cursor[d]++] = src[e]
// ---------------------------------------------------------------------------
__global__ void fill_kernel(const int* __restrict__ src, const int* __restrict__ dst,
                            const int* __restrict__ offsets, int* __restrict__ cursor,
                            int* __restrict__ perm, int E)
{
    int e = blockIdx.x * blockDim.x + threadIdx.x;
    if (e >= E) return;
    int d = dst[e];
    int pos = offsets[d] + atomicAdd(&cursor[d], 1);
    perm[pos] = src[e];
}

// ---------------------------------------------------------------------------
// Gather-aggregate: x[row] = h_dst[row] + sum_{i in CSR(row)} h_src[perm[i]].
// One 64-lane wave per row, float2 per lane. 256-thread block = 4 rows.
// ---------------------------------------------------------------------------
__global__ __launch_bounds__(256) void gather_agg_kernel(
    const float* __restrict__ hsrc, const float* __restrict__ hdst,
    const int* __restrict__ offsets, const int* __restrict__ perm,
    float* __restrict__ x, int N)
{
    int row = blockIdx.x * 4 + (threadIdx.x >> 6);
    if (row >= N) return;
    int lane = (threadIdx.x & 63) << 1;
    int beg = offsets[row], end = offsets[row + 1];
    float2 acc = *reinterpret_cast<const float2*>(hdst + (size_t)row * D + lane);
    int i = beg;
    for (; i + 1 < end; i += 2) {  // 2-edge unroll for ILP
        int s0 = perm[i], s1 = perm[i + 1];
        float2 v0 = *reinterpret_cast<const float2*>(hsrc + (size_t)s0 * D + lane);
        float2 v1 = *reinterpret_cast<const float2*>(hsrc + (size_t)s1 * D + lane);
        acc.x += v0.x + v1.x;
        acc.y += v0.y + v1.y;
    }
    if (i < end) {
        int s0 = perm[i];
        float2 v0 = *reinterpret_cast<const float2*>(hsrc + (size_t)s0 * D + lane);
        acc.x += v0.x;
        acc.y += v0.y;
    }
    *reinterpret_cast<float2*>(x + (size_t)row * D + lane) = acc;
}

// ---------------------------------------------------------------------------
// Y = X @ W  (X: [N][128], W: [128][128]); optionally applies BN+ReLU to X on
// load. Fused epilogue accumulates per-column sum / sum-of-squares of Y.
// ---------------------------------------------------------------------------
template <bool BN_IN>
__global__ __launch_bounds__(256, 2) void gemm_stats_kernel(
    const float* __restrict__ X, const float* __restrict__ W,
    const float* __restrict__ sc, const float* __restrict__ bi,
    float* __restrict__ Y, float* __restrict__ osum, float* __restrict__ osq,
    int N)
{
    __shared__ float Ws[D * D];   // 64 KB
    __shared__ float Xs[32 * D];  // 16 KB
    const int t = threadIdx.x;
    const int row0 = blockIdx.x * 32;

    for (int i = t * 4; i < D * D; i += 256 * 4)
        *reinterpret_cast<float4*>(&Ws[i]) =
            *reinterpret_cast<const float4*>(&W[i]);

    for (int i = t * 4; i < 32 * D; i += 256 * 4) {
        int r = i >> 7, c = i & (D - 1);
        float4 v = make_float4(0.f, 0.f, 0.f, 0.f);
        if (row0 + r < N)
            v = *reinterpret_cast<const float4*>(&X[(size_t)(row0 + r) * D + c]);
        if (BN_IN) {
            float4 s4 = *reinterpret_cast<const float4*>(&sc[c]);
            float4 b4 = *reinterpret_cast<const float4*>(&bi[c]);
            v.x = fmaxf(fmaf(v.x, s4.x, b4.x), 0.f);
            v.y = fmaxf(fmaf(v.y, s4.y, b4.y), 0.f);
            v.z = fmaxf(fmaf(v.z, s4.z, b4.z), 0.f);
            v.w = fmaxf(fmaf(v.w, s4.w, b4.w), 0.f);
        }
        *reinterpret_cast<float4*>(&Xs[i]) = v;
    }
    __syncthreads();

    const int tx = t & 31;
    const int ty = t >> 5;
    const int c0 = tx * 4;
    const int r0 = ty * 4;

    float acc[4][4];
#pragma unroll
    for (int r = 0; r < 4; ++r)
#pragma unroll
        for (int j = 0; j < 4; ++j) acc[r][j] = 0.f;

    for (int k = 0; k < D; k += 4) {
        float w[4][4];
#pragma unroll
        for (int kk = 0; kk < 4; ++kk) {
            float4 w4 = *reinterpret_cast<const float4*>(&Ws[(k + kk) * D + c0]);
            w[kk][0] = w4.x; w[kk][1] = w4.y; w[kk][2] = w4.z; w[kk][3] = w4.w;
        }
#pragma unroll
        for (int r = 0; r < 4; ++r) {
            float4 x4 = *reinterpret_cast<const float4*>(&Xs[(r0 + r) * D + k]);
            float xv[4] = {x4.x, x4.y, x4.z, x4.w};
#pragma unroll
            for (int kk = 0; kk < 4; ++kk)
#pragma unroll
                for (int j = 0; j < 4; ++j)
                    acc[r][j] = fmaf(xv[kk], w[kk][j], acc[r][j]);
        }
    }

#pragma unroll
    for (int r = 0; r < 4; ++r) {
        int row = row0 + r0 + r;
        if (row < N)
            *reinterpret_cast<float4*>(&Y[(size_t)row * D + c0]) =
                make_float4(acc[r][0], acc[r][1], acc[r][2], acc[r][3]);
    }

    __syncthreads();  // done reading Xs; reuse as scratch
    float* s_sum = Xs;
    float* s_sq  = Xs + 8 * D;
    float ps[4] = {0.f, 0.f, 0.f, 0.f}, pq[4] = {0.f, 0.f, 0.f, 0.f};
#pragma unroll
    for (int r = 0; r < 4; ++r) {
        if (row0 + r0 + r < N) {
#pragma unroll
            for (int j = 0; j < 4; ++j) {
                ps[j] += acc[r][j];
                pq[j] += acc[r][j] * acc[r][j];
            }
        }
    }
#pragma unroll
    for (int j = 0; j < 4; ++j) {
        s_sum[ty * D + c0 + j] = ps[j];
        s_sq[ty * D + c0 + j]  = pq[j];
    }
    __syncthreads();
    if (t < D) {
        float a = 0.f, b = 0.f;
#pragma unroll
        for (int g = 0; g < 8; ++g) {
            a += s_sum[g * D + t];
            b += s_sq[g * D + t];
        }
        atomicAdd(&osum[t], a);
        atomicAdd(&osq[t], b);
    }
}

// ---------------------------------------------------------------------------
__global__ void bn_finalize_kernel(const float* __restrict__ sum,
                                   const float* __restrict__ sq,
                                   const float* __restrict__ g,
                                   const float* __restrict__ b,
                                   float* __restrict__ sc,
                                   float* __restrict__ bi, int N)
{
    int c = threadIdx.x;
    float inv_n = 1.f / (float)N;
    float mean = sum[c] * inv_n;
    float var = fmaxf(sq[c] * inv_n - mean * mean, 0.f);
    float s = g[c] * rsqrtf(var + BN_EPS);
    sc[c] = s;
    bi[c] = b[c] - mean * s;
}

// ---------------------------------------------------------------------------
__global__ void bn_relu_out_kernel(const float* __restrict__ Z,
                                   const float* __restrict__ sc,
                                   const float* __restrict__ bi,
                                   float* __restrict__ out, int n4)
{
    for (int i = blockIdx.x * blockDim.x + threadIdx.x; i < n4;
         i += gridDim.x * blockDim.x) {
        float4 v = reinterpret_cast<const float4*>(Z)[i];
        int c = (i * 4) & (D - 1);
        float4 s4 = *reinterpret_cast<const float4*>(&sc[c]);
        float4 b4 = *reinterpret_cast<const float4*>(&bi[c]);
        v.x = fmaxf(fmaf(v.x, s4.x, b4.x), 0.f);
        v.y = fmaxf(fmaf(v.y, s4.y, b4.y), 0.f);
        v.z = fmaxf(fmaf(v.z, s4.z, b4.z), 0.f);
        v.w = fmaxf(fmaf(v.w, s4.w, b4.w), 0.f);
        reinterpret_cast<float4*>(out)[i] = v;
    }
}

// ---------------------------------------------------------------------------
extern "C" void kernel_launch(void* const* d_in, const int* in_sizes, int n_in,
                              void* d_out, int out_size, void* d_ws, size_t ws_size,
                              hipStream_t stream)
{
    const float* h_user   = (const float*)d_in[0];
    const float* h_item   = (const float*)d_in[1];
    const int* src_rates  = (const int*)d_in[2];
    const int* dst_rates  = (const int*)d_in[3];
    const int* src_rev    = (const int*)d_in[4];
    const int* dst_rev    = (const int*)d_in[5];
    const float* W1_rates = (const float*)d_in[6];
    const float* W2_rates = (const float*)d_in[7];
    const float* g1_rates = (const float*)d_in[8];
    const float* b1_rates = (const float*)d_in[9];
    const float* g2_rates = (const float*)d_in[10];
    const float* b2_rates = (const float*)d_in[11];
    const float* W1_rev   = (const float*)d_in[12];
    const float* W2_rev   = (const float*)d_in[13];
    const float* g1_rev   = (const float*)d_in[14];
    const float* b1_rev   = (const float*)d_in[15];
    const float* g2_rev   = (const float*)d_in[16];
    const float* b2_rev   = (const float*)d_in[17];

    const int n_user = in_sizes[0] / D;
    const int n_item = in_sizes[1] / D;
    const int E1 = in_sizes[2];
    const int E2 = in_sizes[4];
    const int n_max = n_user > n_item ? n_user : n_item;
    const int e_max = E1 > E2 ? E1 : E2;

    // Workspace layout: bufA | bufB | stats | counts | offsets | perm
    float* bufA = (float*)d_ws;
    size_t buf_elems = (size_t)n_max * D;
    float* bufB = bufA + buf_elems;
    float* stats = bufB + buf_elems;          // 16*D floats
    int* counts  = (int*)(stats + 16 * D);    // n_max
    int* offsets = counts + n_max;            // n_max + 1
    int* perm    = offsets + n_max + 1;       // e_max

    hipMemsetAsync(stats, 0, 16 * D * sizeof(float), stream);

    float* out_user = (float*)d_out;
    float* out_item = out_user + (size_t)n_user * D;

    auto run_rel = [&](const float* hsrc, const float* hdst, const int* src,
                       const int* dst, int E, int Ndst, const float* W1,
                       const float* W2, const float* g1, const float* b1,
                       const float* g2, const float* b2, float* out, float* st) {
        int eblocks = (E + 255) / 256;

        // --- CSR build ---
        hipMemsetAsync(counts, 0, (size_t)Ndst * sizeof(int), stream);
        hist_kernel<<<eblocks, 256, 0, stream>>>(dst, counts, E);
        scan_kernel<<<1, 1024, 0, stream>>>(counts, offsets, Ndst);
        hipMemsetAsync(counts, 0, (size_t)Ndst * sizeof(int), stream);
        fill_kernel<<<eblocks, 256, 0, stream>>>(src, dst, offsets, counts, perm, E);

        // --- x = h_dst + segment_sum(h_src[perm]) ---
        int ablocks = (Ndst + 3) / 4;
        gather_agg_kernel<<<ablocks, 256, 0, stream>>>(hsrc, hdst, offsets, perm,
                                                       bufA, Ndst);

        float* sum1 = st;         float* sq1 = st + D;
        float* sc1  = st + 2 * D; float* bi1 = st + 3 * D;
        float* sum2 = st + 4 * D; float* sq2 = st + 5 * D;
        float* sc2  = st + 6 * D; float* bi2 = st + 7 * D;

        int gblocks = (Ndst + 31) / 32;
        gemm_stats_kernel<false><<<gblocks, 256, 0, stream>>>(
            bufA, W1, nullptr, nullptr, bufB, sum1, sq1, Ndst);
        bn_finalize_kernel<<<1, D, 0, stream>>>(sum1, sq1, g1, b1, sc1, bi1, Ndst);
        gemm_stats_kernel<true><<<gblocks, 256, 0, stream>>>(
            bufB, W2, sc1, bi1, bufA, sum2, sq2, Ndst);
        bn_finalize_kernel<<<1, D, 0, stream>>>(sum2, sq2, g2, b2, sc2, bi2, Ndst);
        int n4 = (int)((size_t)Ndst * D / 4);
        int oblocks = (n4 + 255) / 256;
        if (oblocks > 2048) oblocks = 2048;
        bn_relu_out_kernel<<<oblocks, 256, 0, stream>>>(bufA, sc2, bi2, out, n4);
    };

    // relation 'rates': user -> item  => out_item
    run_rel(h_user, h_item, src_rates, dst_rates, E1, n_item,
            W1_rates, W2_rates, g1_rates, b1_rates, g2_rates, b2_rates,
            out_item, stats);
    // relation 'rated_by': item -> user => out_user
    run_rel(h_item, h_user, src_rev, dst_rev, E2, n_user,
            W1_rev, W2_rev, g1_rev, b1_rev, g2_rev, b2_rev,
            out_user, stats + 8 * D);
}

// Round 3
// 519.667 us; speedup vs baseline: 4.6818x; 1.2607x over previous
//
#include <hip/hip_runtime.h>

#define D 128
static constexpr float BN_EPS = 1e-5f;

// ---------------------------------------------------------------------------
// CSR build step 1: histogram of dst.
// ---------------------------------------------------------------------------
__global__ void hist_kernel(const int* __restrict__ dst, int* __restrict__ counts,
                            int E)
{
    int e = blockIdx.x * blockDim.x + threadIdx.x;
    if (e < E) atomicAdd(&counts[dst[e]], 1);
}

// ---------------------------------------------------------------------------
// Hierarchical exclusive scan over counts[N] -> offsets[N+1].
// Chunk = 1024 elements per block (256 threads x int4).
// ---------------------------------------------------------------------------
__global__ __launch_bounds__(256) void scan_partial_kernel(
    const int* __restrict__ counts, int* __restrict__ blocksum, int N)
{
    __shared__ int red[256];
    const int t = threadIdx.x;
    const int base = blockIdx.x * 1024 + t * 4;
    int s = 0;
    if (base + 3 < N) {
        int4 q = *reinterpret_cast<const int4*>(counts + base);
        s = q.x + q.y + q.z + q.w;
    } else {
        for (int j = 0; j < 4; ++j)
            if (base + j < N) s += counts[base + j];
    }
    red[t] = s;
    __syncthreads();
    for (int off = 128; off > 0; off >>= 1) {
        if (t < off) red[t] += red[t + off];
        __syncthreads();
    }
    if (t == 0) blocksum[blockIdx.x] = red[0];
}

__global__ __launch_bounds__(256) void scan_partials_kernel(
    int* __restrict__ blocksum, int nblocks)
{
    __shared__ int part[256];
    const int t = threadIdx.x;
    int v = (t < nblocks) ? blocksum[t] : 0;
    part[t] = v;
    __syncthreads();
    for (int off = 1; off < 256; off <<= 1) {
        int tmp = (t >= off) ? part[t - off] : 0;
        __syncthreads();
        part[t] += tmp;
        __syncthreads();
    }
    if (t < nblocks) blocksum[t] = part[t] - v;  // exclusive
}

__global__ __launch_bounds__(256) void scan_block_kernel(
    const int* __restrict__ counts, const int* __restrict__ blocksum,
    int* __restrict__ offsets, int N, int nblocks)
{
    __shared__ int part[256];
    const int b = blockIdx.x, t = threadIdx.x;
    const int base = b * 1024 + t * 4;
    int v[4] = {0, 0, 0, 0};
    if (base + 3 < N) {
        int4 q = *reinterpret_cast<const int4*>(counts + base);
        v[0] = q.x; v[1] = q.y; v[2] = q.z; v[3] = q.w;
    } else {
        for (int j = 0; j < 4; ++j)
            if (base + j < N) v[j] = counts[base + j];
    }
    int s = v[0] + v[1] + v[2] + v[3];
    part[t] = s;
    __syncthreads();
    for (int off = 1; off < 256; off <<= 1) {
        int tmp = (t >= off) ? part[t - off] : 0;
        __syncthreads();
        part[t] += tmp;
        __syncthreads();
    }
    int excl = part[t] - s + blocksum[b];
    int o0 = excl, o1 = o0 + v[0], o2 = o1 + v[1], o3 = o2 + v[2];
    if (base + 3 < N) {
        *reinterpret_cast<int4*>(offsets + base) = make_int4(o0, o1, o2, o3);
    } else {
        int oo[4] = {o0, o1, o2, o3};
        for (int j = 0; j < 4; ++j)
            if (base + j < N) offsets[base + j] = oo[j];
    }
    if (b == nblocks - 1 && t == 255) offsets[N] = blocksum[b] + part[255];
}

// ---------------------------------------------------------------------------
// CSR build step 3: place src into perm using counts as a down-counter
// (no cursor array, no second memset).
// ---------------------------------------------------------------------------
__global__ void fill_kernel(const int* __restrict__ src, const int* __restrict__ dst,
                            const int* __restrict__ offsets, int* __restrict__ counts,
                            int* __restrict__ perm, int E)
{
    int e = blockIdx.x * blockDim.x + threadIdx.x;
    if (e >= E) return;
    int d = dst[e];
    int r = atomicSub(&counts[d], 1);  // old value in [1..deg]
    perm[offsets[d] + r - 1] = src[e];
}

// ---------------------------------------------------------------------------
// Gather-aggregate: x[row] = h_dst[row] + sum_{i in CSR(row)} h_src[perm[i]].
// One 64-lane wave per row, float2 per lane. 256-thread block = 4 rows.
// ---------------------------------------------------------------------------
__global__ __launch_bounds__(256) void gather_agg_kernel(
    const float* __restrict__ hsrc, const float* __restrict__ hdst,
    const int* __restrict__ offsets, const int* __restrict__ perm,
    float* __restrict__ x, int N)
{
    int row = blockIdx.x * 4 + (threadIdx.x >> 6);
    if (row >= N) return;
    int lane = (threadIdx.x & 63) << 1;
    int beg = offsets[row], end = offsets[row + 1];
    float2 acc = *reinterpret_cast<const float2*>(hdst + (size_t)row * D + lane);
    int i = beg;
    for (; i + 1 < end; i += 2) {
        int s0 = perm[i], s1 = perm[i + 1];
        float2 v0 = *reinterpret_cast<const float2*>(hsrc + (size_t)s0 * D + lane);
        float2 v1 = *reinterpret_cast<const float2*>(hsrc + (size_t)s1 * D + lane);
        acc.x += v0.x + v1.x;
        acc.y += v0.y + v1.y;
    }
    if (i < end) {
        int s0 = perm[i];
        float2 v0 = *reinterpret_cast<const float2*>(hsrc + (size_t)s0 * D + lane);
        acc.x += v0.x;
        acc.y += v0.y;
    }
    *reinterpret_cast<float2*>(x + (size_t)row * D + lane) = acc;
}

// ---------------------------------------------------------------------------
// Y = X @ W  (X: [N][128], W: [128][128]); optionally applies BN+ReLU to X on
// load. Fused epilogue accumulates per-column sum / sum-of-squares of Y.
// ---------------------------------------------------------------------------
template <bool BN_IN>
__global__ __launch_bounds__(256, 2) void gemm_stats_kernel(
    const float* __restrict__ X, const float* __restrict__ W,
    const float* __restrict__ sc, const float* __restrict__ bi,
    float* __restrict__ Y, float* __restrict__ osum, float* __restrict__ osq,
    int N)
{
    __shared__ float Ws[D * D];   // 64 KB
    __shared__ float Xs[32 * D];  // 16 KB
    const int t = threadIdx.x;
    const int row0 = blockIdx.x * 32;

    for (int i = t * 4; i < D * D; i += 256 * 4)
        *reinterpret_cast<float4*>(&Ws[i]) =
            *reinterpret_cast<const float4*>(&W[i]);

    for (int i = t * 4; i < 32 * D; i += 256 * 4) {
        int r = i >> 7, c = i & (D - 1);
        float4 v = make_float4(0.f, 0.f, 0.f, 0.f);
        if (row0 + r < N)
            v = *reinterpret_cast<const float4*>(&X[(size_t)(row0 + r) * D + c]);
        if (BN_IN) {
            float4 s4 = *reinterpret_cast<const float4*>(&sc[c]);
            float4 b4 = *reinterpret_cast<const float4*>(&bi[c]);
            v.x = fmaxf(fmaf(v.x, s4.x, b4.x), 0.f);
            v.y = fmaxf(fmaf(v.y, s4.y, b4.y), 0.f);
            v.z = fmaxf(fmaf(v.z, s4.z, b4.z), 0.f);
            v.w = fmaxf(fmaf(v.w, s4.w, b4.w), 0.f);
        }
        *reinterpret_cast<float4*>(&Xs[i]) = v;
    }
    __syncthreads();

    const int tx = t & 31;
    const int ty = t >> 5;
    const int c0 = tx * 4;
    const int r0 = ty * 4;

    float acc[4][4];
#pragma unroll
    for (int r = 0; r < 4; ++r)
#pragma unroll
        for (int j = 0; j < 4; ++j) acc[r][j] = 0.f;

    for (int k = 0; k < D; k += 4) {
        float w[4][4];
#pragma unroll
        for (int kk = 0; kk < 4; ++kk) {
            float4 w4 = *reinterpret_cast<const float4*>(&Ws[(k + kk) * D + c0]);
            w[kk][0] = w4.x; w[kk][1] = w4.y; w[kk][2] = w4.z; w[kk][3] = w4.w;
        }
#pragma unroll
        for (int r = 0; r < 4; ++r) {
            float4 x4 = *reinterpret_cast<const float4*>(&Xs[(r0 + r) * D + k]);
            float xv[4] = {x4.x, x4.y, x4.z, x4.w};
#pragma unroll
            for (int kk = 0; kk < 4; ++kk)
#pragma unroll
                for (int j = 0; j < 4; ++j)
                    acc[r][j] = fmaf(xv[kk], w[kk][j], acc[r][j]);
        }
    }

#pragma unroll
    for (int r = 0; r < 4; ++r) {
        int row = row0 + r0 + r;
        if (row < N)
            *reinterpret_cast<float4*>(&Y[(size_t)row * D + c0]) =
                make_float4(acc[r][0], acc[r][1], acc[r][2], acc[r][3]);
    }

    __syncthreads();  // done reading Xs; reuse as scratch
    float* s_sum = Xs;
    float* s_sq  = Xs + 8 * D;
    float ps[4] = {0.f, 0.f, 0.f, 0.f}, pq[4] = {0.f, 0.f, 0.f, 0.f};
#pragma unroll
    for (int r = 0; r < 4; ++r) {
        if (row0 + r0 + r < N) {
#pragma unroll
            for (int j = 0; j < 4; ++j) {
                ps[j] += acc[r][j];
                pq[j] += acc[r][j] * acc[r][j];
            }
        }
    }
#pragma unroll
    for (int j = 0; j < 4; ++j) {
        s_sum[ty * D + c0 + j] = ps[j];
        s_sq[ty * D + c0 + j]  = pq[j];
    }
    __syncthreads();
    if (t < D) {
        float a = 0.f, b = 0.f;
#pragma unroll
        for (int g = 0; g < 8; ++g) {
            a += s_sum[g * D + t];
            b += s_sq[g * D + t];
        }
        atomicAdd(&osum[t], a);
        atomicAdd(&osq[t], b);
    }
}

// ---------------------------------------------------------------------------
__global__ void bn_finalize_kernel(const float* __restrict__ sum,
                                   const float* __restrict__ sq,
                                   const float* __restrict__ g,
                                   const float* __restrict__ b,
                                   float* __restrict__ sc,
                                   float* __restrict__ bi, int N)
{
    int c = threadIdx.x;
    float inv_n = 1.f / (float)N;
    float mean = sum[c] * inv_n;
    float var = fmaxf(sq[c] * inv_n - mean * mean, 0.f);
    float s = g[c] * rsqrtf(var + BN_EPS);
    sc[c] = s;
    bi[c] = b[c] - mean * s;
}

// ---------------------------------------------------------------------------
__global__ void bn_relu_out_kernel(const float* __restrict__ Z,
                                   const float* __restrict__ sc,
                                   const float* __restrict__ bi,
                                   float* __restrict__ out, int n4)
{
    for (int i = blockIdx.x * blockDim.x + threadIdx.x; i < n4;
         i += gridDim.x * blockDim.x) {
        float4 v = reinterpret_cast<const float4*>(Z)[i];
        int c = (i * 4) & (D - 1);
        float4 s4 = *reinterpret_cast<const float4*>(&sc[c]);
        float4 b4 = *reinterpret_cast<const float4*>(&bi[c]);
        v.x = fmaxf(fmaf(v.x, s4.x, b4.x), 0.f);
        v.y = fmaxf(fmaf(v.y, s4.y, b4.y), 0.f);
        v.z = fmaxf(fmaf(v.z, s4.z, b4.z), 0.f);
        v.w = fmaxf(fmaf(v.w, s4.w, b4.w), 0.f);
        reinterpret_cast<float4*>(out)[i] = v;
    }
}

// ---------------------------------------------------------------------------
extern "C" void kernel_launch(void* const* d_in, const int* in_sizes, int n_in,
                              void* d_out, int out_size, void* d_ws, size_t ws_size,
                              hipStream_t stream)
{
    const float* h_user   = (const float*)d_in[0];
    const float* h_item   = (const float*)d_in[1];
    const int* src_rates  = (const int*)d_in[2];
    const int* dst_rates  = (const int*)d_in[3];
    const int* src_rev    = (const int*)d_in[4];
    const int* dst_rev    = (const int*)d_in[5];
    const float* W1_rates = (const float*)d_in[6];
    const float* W2_rates = (const float*)d_in[7];
    const float* g1_rates = (const float*)d_in[8];
    const float* b1_rates = (const float*)d_in[9];
    const float* g2_rates = (const float*)d_in[10];
    const float* b2_rates = (const float*)d_in[11];
    const float* W1_rev   = (const float*)d_in[12];
    const float* W2_rev   = (const float*)d_in[13];
    const float* g1_rev   = (const float*)d_in[14];
    const float* b1_rev   = (const float*)d_in[15];
    const float* g2_rev   = (const float*)d_in[16];
    const float* b2_rev   = (const float*)d_in[17];

    const int n_user = in_sizes[0] / D;
    const int n_item = in_sizes[1] / D;
    const int E1 = in_sizes[2];
    const int E2 = in_sizes[4];
    const int n_max = n_user > n_item ? n_user : n_item;
    const int e_max = E1 > E2 ? E1 : E2;

    // Workspace layout: bufA | bufB | stats | counts | offsets | blocksum | perm
    float* bufA = (float*)d_ws;
    size_t buf_elems = (size_t)n_max * D;
    float* bufB = bufA + buf_elems;
    float* stats = bufB + buf_elems;           // 16*D floats
    int* counts   = (int*)(stats + 16 * D);    // n_max
    int* offsets  = counts + n_max;            // n_max + 1
    int* blocksum = offsets + n_max + 1;       // 256
    int* perm     = blocksum + 256;            // e_max

    hipMemsetAsync(stats, 0, 16 * D * sizeof(float), stream);

    float* out_user = (float*)d_out;
    float* out_item = out_user + (size_t)n_user * D;

    auto run_rel = [&](const float* hsrc, const float* hdst, const int* src,
                       const int* dst, int E, int Ndst, const float* W1,
                       const float* W2, const float* g1, const float* b1,
                       const float* g2, const float* b2, float* out, float* st) {
        int eblocks = (E + 255) / 256;
        int nscan = (Ndst + 1023) / 1024;  // <= 256 (N <= 262144)

        // --- CSR build ---
        hipMemsetAsync(counts, 0, (size_t)Ndst * sizeof(int), stream);
        hist_kernel<<<eblocks, 256, 0, stream>>>(dst, counts, E);
        scan_partial_kernel<<<nscan, 256, 0, stream>>>(counts, blocksum, Ndst);
        scan_partials_kernel<<<1, 256, 0, stream>>>(blocksum, nscan);
        scan_block_kernel<<<nscan, 256, 0, stream>>>(counts, blocksum, offsets,
                                                     Ndst, nscan);
        fill_kernel<<<eblocks, 256, 0, stream>>>(src, dst, offsets, counts, perm, E);

        // --- x = h_dst + segment_sum(h_src[perm]) ---
        int ablocks = (Ndst + 3) / 4;
        gather_agg_kernel<<<ablocks, 256, 0, stream>>>(hsrc, hdst, offsets, perm,
                                                       bufA, Ndst);

        float* sum1 = st;         float* sq1 = st + D;
        float* sc1  = st + 2 * D; float* bi1 = st + 3 * D;
        float* sum2 = st + 4 * D; float* sq2 = st + 5 * D;
        float* sc2  = st + 6 * D; float* bi2 = st + 7 * D;

        int gblocks = (Ndst + 31) / 32;
        gemm_stats_kernel<false><<<gblocks, 256, 0, stream>>>(
            bufA, W1, nullptr, nullptr, bufB, sum1, sq1, Ndst);
        bn_finalize_kernel<<<1, D, 0, stream>>>(sum1, sq1, g1, b1, sc1, bi1, Ndst);
        gemm_stats_kernel<true><<<gblocks, 256, 0, stream>>>(
            bufB, W2, sc1, bi1, bufA, sum2, sq2, Ndst);
        bn_finalize_kernel<<<1, D, 0, stream>>>(sum2, sq2, g2, b2, sc2, bi2, Ndst);
        int n4 = (int)((size_t)Ndst * D / 4);
        int oblocks = (n4 + 255) / 256;
        if (oblocks > 2048) oblocks = 2048;
        bn_relu_out_kernel<<<oblocks, 256, 0, stream>>>(bufA, sc2, bi2, out, n4);
    };

    // relation 'rates': user -> item  => out_item
    run_rel(h_user, h_item, src_rates, dst_rates, E1, n_item,
            W1_rates, W2_rates, g1_rates, b1_rates, g2_rates, b2_rates,
            out_item, stats);
    // relation 'rated_by': item -> user => out_user
    run_rel(h_item, h_user, src_rev, dst_rev, E2, n_user,
            W1_rev, W2_rev, g1_rev, b1_rev, g2_rev, b2_rev,
            out_user, stats + 8 * D);
}

// Round 4
// 427.303 us; speedup vs baseline: 5.6938x; 1.2162x over previous
//
#include <hip/hip_runtime.h>

#define D 128
static constexpr float BN_EPS = 1e-5f;

// ---------------------------------------------------------------------------
// CSR build step 1: histogram of dst.
// ---------------------------------------------------------------------------
__global__ void hist_kernel(const int* __restrict__ dst, int* __restrict__ counts,
                            int E)
{
    int e = blockIdx.x * blockDim.x + threadIdx.x;
    if (e < E) atomicAdd(&counts[dst[e]], 1);
}

// ---------------------------------------------------------------------------
// Hierarchical exclusive scan over counts[N] -> offsets[N+1].
// ---------------------------------------------------------------------------
__global__ __launch_bounds__(256) void scan_partial_kernel(
    const int* __restrict__ counts, int* __restrict__ blocksum, int N)
{
    __shared__ int red[256];
    const int t = threadIdx.x;
    const int base = blockIdx.x * 1024 + t * 4;
    int s = 0;
    if (base + 3 < N) {
        int4 q = *reinterpret_cast<const int4*>(counts + base);
        s = q.x + q.y + q.z + q.w;
    } else {
        for (int j = 0; j < 4; ++j)
            if (base + j < N) s += counts[base + j];
    }
    red[t] = s;
    __syncthreads();
    for (int off = 128; off > 0; off >>= 1) {
        if (t < off) red[t] += red[t + off];
        __syncthreads();
    }
    if (t == 0) blocksum[blockIdx.x] = red[0];
}

__global__ __launch_bounds__(256) void scan_partials_kernel(
    int* __restrict__ blocksum, int nblocks)
{
    __shared__ int part[256];
    const int t = threadIdx.x;
    int v = (t < nblocks) ? blocksum[t] : 0;
    part[t] = v;
    __syncthreads();
    for (int off = 1; off < 256; off <<= 1) {
        int tmp = (t >= off) ? part[t - off] : 0;
        __syncthreads();
        part[t] += tmp;
        __syncthreads();
    }
    if (t < nblocks) blocksum[t] = part[t] - v;  // exclusive
}

__global__ __launch_bounds__(256) void scan_block_kernel(
    const int* __restrict__ counts, const int* __restrict__ blocksum,
    int* __restrict__ offsets, int N, int nblocks)
{
    __shared__ int part[256];
    const int b = blockIdx.x, t = threadIdx.x;
    const int base = b * 1024 + t * 4;
    int v[4] = {0, 0, 0, 0};
    if (base + 3 < N) {
        int4 q = *reinterpret_cast<const int4*>(counts + base);
        v[0] = q.x; v[1] = q.y; v[2] = q.z; v[3] = q.w;
    } else {
        for (int j = 0; j < 4; ++j)
            if (base + j < N) v[j] = counts[base + j];
    }
    int s = v[0] + v[1] + v[2] + v[3];
    part[t] = s;
    __syncthreads();
    for (int off = 1; off < 256; off <<= 1) {
        int tmp = (t >= off) ? part[t - off] : 0;
        __syncthreads();
        part[t] += tmp;
        __syncthreads();
    }
    int excl = part[t] - s + blocksum[b];
    int o0 = excl, o1 = o0 + v[0], o2 = o1 + v[1], o3 = o2 + v[2];
    if (base + 3 < N) {
        *reinterpret_cast<int4*>(offsets + base) = make_int4(o0, o1, o2, o3);
    } else {
        int oo[4] = {o0, o1, o2, o3};
        for (int j = 0; j < 4; ++j)
            if (base + j < N) offsets[base + j] = oo[j];
    }
    if (b == nblocks - 1 && t == 255) offsets[N] = blocksum[b] + part[255];
}

// ---------------------------------------------------------------------------
// CSR build step 3: place src into perm using counts as a down-counter.
// ---------------------------------------------------------------------------
__global__ void fill_kernel(const int* __restrict__ src, const int* __restrict__ dst,
                            const int* __restrict__ offsets, int* __restrict__ counts,
                            int* __restrict__ perm, int E)
{
    int e = blockIdx.x * blockDim.x + threadIdx.x;
    if (e >= E) return;
    int d = dst[e];
    int r = atomicSub(&counts[d], 1);  // old value in [1..deg]
    perm[offsets[d] + r - 1] = src[e];
}

// ---------------------------------------------------------------------------
// Gather-aggregate: x[row] = h_dst[row] + sum_{i in CSR(row)} h_src[perm[i]].
// One 64-lane wave per row, float2 per lane.
// ---------------------------------------------------------------------------
__global__ __launch_bounds__(256) void gather_agg_kernel(
    const float* __restrict__ hsrc, const float* __restrict__ hdst,
    const int* __restrict__ offsets, const int* __restrict__ perm,
    float* __restrict__ x, int N)
{
    int row = blockIdx.x * 4 + (threadIdx.x >> 6);
    if (row >= N) return;
    int lane = (threadIdx.x & 63) << 1;
    int beg = offsets[row], end = offsets[row + 1];
    float2 acc = *reinterpret_cast<const float2*>(hdst + (size_t)row * D + lane);
    int i = beg;
    for (; i + 1 < end; i += 2) {
        int s0 = perm[i], s1 = perm[i + 1];
        float2 v0 = *reinterpret_cast<const float2*>(hsrc + (size_t)s0 * D + lane);
        float2 v1 = *reinterpret_cast<const float2*>(hsrc + (size_t)s1 * D + lane);
        acc.x += v0.x + v1.x;
        acc.y += v0.y + v1.y;
    }
    if (i < end) {
        int s0 = perm[i];
        float2 v0 = *reinterpret_cast<const float2*>(hsrc + (size_t)s0 * D + lane);
        acc.x += v0.x;
        acc.y += v0.y;
    }
    *reinterpret_cast<float2*>(x + (size_t)row * D + lane) = acc;
}

// ---------------------------------------------------------------------------
// Persistent-W GEMM: Y = X @ W with optional BN+ReLU applied to X on load.
// Block keeps W in LDS across a grid-stride loop over 32-row tiles; the next
// X tile is prefetched into registers during compute. Column sum/sumsq of Y
// accumulate in registers across tiles -> one atomic set per block.
// LDS: W 64KB + X tile 16KB = 80KB -> 2 blocks/CU (8 waves).
// ---------------------------------------------------------------------------
template <bool BN_IN>
__global__ __launch_bounds__(256, 2) void gemm_stats_kernel(
    const float* __restrict__ X, const float* __restrict__ W,
    const float* __restrict__ sc, const float* __restrict__ bi,
    float* __restrict__ Y, float* __restrict__ osum, float* __restrict__ osq,
    int N, int ntiles)
{
    __shared__ float Ws[D * D];   // 64 KB
    __shared__ float Xs[32 * D];  // 16 KB
    const int t = threadIdx.x;

    // Load W once per block.
    for (int i = t * 4; i < D * D; i += 256 * 4)
        *reinterpret_cast<float4*>(&Ws[i]) =
            *reinterpret_cast<const float4*>(&W[i]);

    // Prefetch lane mapping: thread covers rows rb, rb+8, rb+16, rb+24 at
    // float4-column c4 (columns c4*4..c4*4+3, identical for all 4 rows).
    const int c4 = t & 31;
    const int rb = t >> 5;
    float4 scv, biv;
    if (BN_IN) {
        scv = *reinterpret_cast<const float4*>(&sc[c4 * 4]);
        biv = *reinterpret_cast<const float4*>(&bi[c4 * 4]);
    }

    float4 pf[4];
    auto load_tile = [&](int tile) {
#pragma unroll
        for (int j = 0; j < 4; ++j) {
            int row = tile * 32 + rb + 8 * j;
            float4 v = make_float4(0.f, 0.f, 0.f, 0.f);
            if (row < N) {
                v = *reinterpret_cast<const float4*>(&X[(size_t)row * D + c4 * 4]);
                if (BN_IN) {
                    v.x = fmaxf(fmaf(v.x, scv.x, biv.x), 0.f);
                    v.y = fmaxf(fmaf(v.y, scv.y, biv.y), 0.f);
                    v.z = fmaxf(fmaf(v.z, scv.z, biv.z), 0.f);
                    v.w = fmaxf(fmaf(v.w, scv.w, biv.w), 0.f);
                }
            }
            pf[j] = v;   // rows >= N stay exactly 0 (post-BN) -> Y rows 0
        }
    };

    // Compute mapping: 4x4 outputs per thread.
    const int tx = t & 31;
    const int ty = t >> 5;
    const int c0 = tx * 4;
    const int r0 = ty * 4;

    float ps[4] = {0.f, 0.f, 0.f, 0.f}, pq[4] = {0.f, 0.f, 0.f, 0.f};

    int tile = blockIdx.x;
    if (tile < ntiles) load_tile(tile);

    for (; tile < ntiles; tile += gridDim.x) {
        // Commit prefetched tile to LDS.
#pragma unroll
        for (int j = 0; j < 4; ++j)
            *reinterpret_cast<float4*>(&Xs[(rb + 8 * j) * D + c4 * 4]) = pf[j];
        __syncthreads();

        // Issue next tile's global loads; latency hides under compute.
        int nxt = tile + gridDim.x;
        if (nxt < ntiles) load_tile(nxt);

        float acc[4][4];
#pragma unroll
        for (int r = 0; r < 4; ++r)
#pragma unroll
            for (int j = 0; j < 4; ++j) acc[r][j] = 0.f;

        for (int k = 0; k < D; k += 4) {
            float w[4][4];
#pragma unroll
            for (int kk = 0; kk < 4; ++kk) {
                float4 w4 = *reinterpret_cast<const float4*>(&Ws[(k + kk) * D + c0]);
                w[kk][0] = w4.x; w[kk][1] = w4.y; w[kk][2] = w4.z; w[kk][3] = w4.w;
            }
#pragma unroll
            for (int r = 0; r < 4; ++r) {
                float4 x4 = *reinterpret_cast<const float4*>(&Xs[(r0 + r) * D + k]);
                float xv[4] = {x4.x, x4.y, x4.z, x4.w};
#pragma unroll
                for (int kk = 0; kk < 4; ++kk)
#pragma unroll
                    for (int j = 0; j < 4; ++j)
                        acc[r][j] = fmaf(xv[kk], w[kk][j], acc[r][j]);
            }
        }

        const int row0 = tile * 32;
#pragma unroll
        for (int r = 0; r < 4; ++r) {
            int row = row0 + r0 + r;
            if (row < N)
                *reinterpret_cast<float4*>(&Y[(size_t)row * D + c0]) =
                    make_float4(acc[r][0], acc[r][1], acc[r][2], acc[r][3]);
            // Padded rows have X==0 -> acc==0 -> zero contribution to stats.
#pragma unroll
            for (int j = 0; j < 4; ++j) {
                ps[j] += acc[r][j];
                pq[j] += acc[r][j] * acc[r][j];
            }
        }
        __syncthreads();  // all waves done with Xs before next commit
    }

    // Block-level stats reduction (Xs is free here).
    float* s_sum = Xs;            // [8][D]
    float* s_sq  = Xs + 8 * D;    // [8][D]
#pragma unroll
    for (int j = 0; j < 4; ++j) {
        s_sum[ty * D + c0 + j] = ps[j];
        s_sq[ty * D + c0 + j]  = pq[j];
    }
    __syncthreads();
    if (t < D) {
        float a = 0.f, b = 0.f;
#pragma unroll
        for (int g = 0; g < 8; ++g) {
            a += s_sum[g * D + t];
            b += s_sq[g * D + t];
        }
        atomicAdd(&osum[t], a);
        atomicAdd(&osq[t], b);
    }
}

// ---------------------------------------------------------------------------
__global__ void bn_finalize_kernel(const float* __restrict__ sum,
                                   const float* __restrict__ sq,
                                   const float* __restrict__ g,
                                   const float* __restrict__ b,
                                   float* __restrict__ sc,
                                   float* __restrict__ bi, int N)
{
    int c = threadIdx.x;
    float inv_n = 1.f / (float)N;
    float mean = sum[c] * inv_n;
    float var = fmaxf(sq[c] * inv_n - mean * mean, 0.f);
    float s = g[c] * rsqrtf(var + BN_EPS);
    sc[c] = s;
    bi[c] = b[c] - mean * s;
}

// ---------------------------------------------------------------------------
__global__ void bn_relu_out_kernel(const float* __restrict__ Z,
                                   const float* __restrict__ sc,
                                   const float* __restrict__ bi,
                                   float* __restrict__ out, int n4)
{
    for (int i = blockIdx.x * blockDim.x + threadIdx.x; i < n4;
         i += gridDim.x * blockDim.x) {
        float4 v = reinterpret_cast<const float4*>(Z)[i];
        int c = (i * 4) & (D - 1);
        float4 s4 = *reinterpret_cast<const float4*>(&sc[c]);
        float4 b4 = *reinterpret_cast<const float4*>(&bi[c]);
        v.x = fmaxf(fmaf(v.x, s4.x, b4.x), 0.f);
        v.y = fmaxf(fmaf(v.y, s4.y, b4.y), 0.f);
        v.z = fmaxf(fmaf(v.z, s4.z, b4.z), 0.f);
        v.w = fmaxf(fmaf(v.w, s4.w, b4.w), 0.f);
        reinterpret_cast<float4*>(out)[i] = v;
    }
}

// ---------------------------------------------------------------------------
extern "C" void kernel_launch(void* const* d_in, const int* in_sizes, int n_in,
                              void* d_out, int out_size, void* d_ws, size_t ws_size,
                              hipStream_t stream)
{
    const float* h_user   = (const float*)d_in[0];
    const float* h_item   = (const float*)d_in[1];
    const int* src_rates  = (const int*)d_in[2];
    const int* dst_rates  = (const int*)d_in[3];
    const int* src_rev    = (const int*)d_in[4];
    const int* dst_rev    = (const int*)d_in[5];
    const float* W1_rates = (const float*)d_in[6];
    const float* W2_rates = (const float*)d_in[7];
    const float* g1_rates = (const float*)d_in[8];
    const float* b1_rates = (const float*)d_in[9];
    const float* g2_rates = (const float*)d_in[10];
    const float* b2_rates = (const float*)d_in[11];
    const float* W1_rev   = (const float*)d_in[12];
    const float* W2_rev   = (const float*)d_in[13];
    const float* g1_rev   = (const float*)d_in[14];
    const float* b1_rev   = (const float*)d_in[15];
    const float* g2_rev   = (const float*)d_in[16];
    const float* b2_rev   = (const float*)d_in[17];

    const int n_user = in_sizes[0] / D;
    const int n_item = in_sizes[1] / D;
    const int E1 = in_sizes[2];
    const int E2 = in_sizes[4];
    const int n_max = n_user > n_item ? n_user : n_item;

    // Workspace layout: bufA | bufB | stats | counts | offsets | blocksum | perm
    float* bufA = (float*)d_ws;
    size_t buf_elems = (size_t)n_max * D;
    float* bufB = bufA + buf_elems;
    float* stats = bufB + buf_elems;           // 16*D floats
    int* counts   = (int*)(stats + 16 * D);    // n_max
    int* offsets  = counts + n_max;            // n_max + 1
    int* blocksum = offsets + n_max + 1;       // 256
    int* perm     = blocksum + 256;            // e_max

    hipMemsetAsync(stats, 0, 16 * D * sizeof(float), stream);

    float* out_user = (float*)d_out;
    float* out_item = out_user + (size_t)n_user * D;

    auto run_rel = [&](const float* hsrc, const float* hdst, const int* src,
                       const int* dst, int E, int Ndst, const float* W1,
                       const float* W2, const float* g1, const float* b1,
                       const float* g2, const float* b2, float* out, float* st) {
        int eblocks = (E + 255) / 256;
        int nscan = (Ndst + 1023) / 1024;  // <= 256

        // --- CSR build ---
        hipMemsetAsync(counts, 0, (size_t)Ndst * sizeof(int), stream);
        hist_kernel<<<eblocks, 256, 0, stream>>>(dst, counts, E);
        scan_partial_kernel<<<nscan, 256, 0, stream>>>(counts, blocksum, Ndst);
        scan_partials_kernel<<<1, 256, 0, stream>>>(blocksum, nscan);
        scan_block_kernel<<<nscan, 256, 0, stream>>>(counts, blocksum, offsets,
                                                     Ndst, nscan);
        fill_kernel<<<eblocks, 256, 0, stream>>>(src, dst, offsets, counts, perm, E);

        // --- x = h_dst + segment_sum(h_src[perm]) ---
        int ablocks = (Ndst + 3) / 4;
        gather_agg_kernel<<<ablocks, 256, 0, stream>>>(hsrc, hdst, offsets, perm,
                                                       bufA, Ndst);

        float* sum1 = st;         float* sq1 = st + D;
        float* sc1  = st + 2 * D; float* bi1 = st + 3 * D;
        float* sum2 = st + 4 * D; float* sq2 = st + 5 * D;
        float* sc2  = st + 6 * D; float* bi2 = st + 7 * D;

        int ntiles = (Ndst + 31) / 32;
        int gblocks = ntiles < 512 ? ntiles : 512;
        gemm_stats_kernel<false><<<gblocks, 256, 0, stream>>>(
            bufA, W1, nullptr, nullptr, bufB, sum1, sq1, Ndst, ntiles);
        bn_finalize_kernel<<<1, D, 0, stream>>>(sum1, sq1, g1, b1, sc1, bi1, Ndst);
        gemm_stats_kernel<true><<<gblocks, 256, 0, stream>>>(
            bufB, W2, sc1, bi1, bufA, sum2, sq2, Ndst, ntiles);
        bn_finalize_kernel<<<1, D, 0, stream>>>(sum2, sq2, g2, b2, sc2, bi2, Ndst);
        int n4 = (int)((size_t)Ndst * D / 4);
        int oblocks = (n4 + 255) / 256;
        if (oblocks > 2048) oblocks = 2048;
        bn_relu_out_kernel<<<oblocks, 256, 0, stream>>>(bufA, sc2, bi2, out, n4);
    };

    // relation 'rates': user -> item  => out_item
    run_rel(h_user, h_item, src_rates, dst_rates, E1, n_item,
            W1_rates, W2_rates, g1_rates, b1_rates, g2_rates, b2_rates,
            out_item, stats);
    // relation 'rated_by': item -> user => out_user
    run_rel(h_item, h_user, src_rev, dst_rev, E2, n_user,
            W1_rev, W2_rev, g1_rev, b1_rev, g2_rev, b2_rev,
            out_user, stats + 8 * D);
}

// Round 5
// 347.502 us; speedup vs baseline: 7.0013x; 1.2296x over previous
//
#include <hip/hip_runtime.h>

#define D 128
static constexpr float BN_EPS = 1e-5f;

typedef __attribute__((ext_vector_type(8))) short short8;
typedef __attribute__((ext_vector_type(4))) float f32x4;

// ---------------------------------------------------------------------------
// bf16 helpers (RNE)
// ---------------------------------------------------------------------------
__device__ __forceinline__ unsigned short f2bf(float f)
{
    unsigned u = __builtin_bit_cast(unsigned, f);
    unsigned r = u + 0x7fffu + ((u >> 16) & 1u);
    return (unsigned short)(r >> 16);
}
__device__ __forceinline__ float bflo(unsigned u)
{
    return __builtin_bit_cast(float, u << 16);
}
__device__ __forceinline__ float bfhi(unsigned u)
{
    return __builtin_bit_cast(float, u & 0xffff0000u);
}

// ---------------------------------------------------------------------------
// h (f32) -> bf16 tables, both node types in one kernel. Work unit = 8 elems.
// ---------------------------------------------------------------------------
__global__ void convert_h_kernel(const float* __restrict__ hu,
                                 const float* __restrict__ hi,
                                 unsigned short* __restrict__ bu,
                                 unsigned short* __restrict__ bi8,
                                 int nu8, int ni8)
{
    int i = blockIdx.x * blockDim.x + threadIdx.x;
    if (i >= nu8 + ni8) return;
    const float* s; unsigned short* d; int o;
    if (i < nu8) { s = hu; d = bu; o = i; }
    else         { s = hi; d = bi8; o = i - nu8; }
    float4 v0 = reinterpret_cast<const float4*>(s)[o * 2];
    float4 v1 = reinterpret_cast<const float4*>(s)[o * 2 + 1];
    uint4 r;
    r.x = (unsigned)f2bf(v0.x) | ((unsigned)f2bf(v0.y) << 16);
    r.y = (unsigned)f2bf(v0.z) | ((unsigned)f2bf(v0.w) << 16);
    r.z = (unsigned)f2bf(v1.x) | ((unsigned)f2bf(v1.y) << 16);
    r.w = (unsigned)f2bf(v1.z) | ((unsigned)f2bf(v1.w) << 16);
    reinterpret_cast<uint4*>(d)[o] = r;
}

// ---------------------------------------------------------------------------
// W [k][n] f32 -> Wt [n][k] bf16 for the 4 weight matrices. 64 blocks.
// ---------------------------------------------------------------------------
__global__ __launch_bounds__(256) void prep_w_kernel(
    const float* __restrict__ Wa, const float* __restrict__ Wb,
    const float* __restrict__ Wc, const float* __restrict__ Wd,
    unsigned short* __restrict__ wt)
{
    const int wsel = blockIdx.x >> 4;
    const float* W = wsel == 0 ? Wa : wsel == 1 ? Wb : wsel == 2 ? Wc : Wd;
    unsigned short* out = wt + (size_t)wsel * D * D;
    const int tile = blockIdx.x & 15;
    const int k0 = (tile >> 2) * 32, n0 = (tile & 3) * 32;
    __shared__ float s[32][33];
    const int t = threadIdx.x;
    const int r = t >> 3, c = (t & 7) * 4;
    float4 v = *reinterpret_cast<const float4*>(W + (size_t)(k0 + r) * D + n0 + c);
    s[r][c] = v.x; s[r][c + 1] = v.y; s[r][c + 2] = v.z; s[r][c + 3] = v.w;
    __syncthreads();
    // out[n0+r][k0+c+j] = W[k0+c+j][n0+r] = s[c+j][r]
    unsigned lo = (unsigned)f2bf(s[c][r]) | ((unsigned)f2bf(s[c + 1][r]) << 16);
    unsigned hi = (unsigned)f2bf(s[c + 2][r]) | ((unsigned)f2bf(s[c + 3][r]) << 16);
    *reinterpret_cast<uint2*>(out + (size_t)(n0 + r) * D + k0 + c) =
        make_uint2(lo, hi);
}

// ---------------------------------------------------------------------------
// CSR build: histogram, hierarchical scan, fill (downcounter).
// ---------------------------------------------------------------------------
__global__ void hist_kernel(const int* __restrict__ dst, int* __restrict__ counts,
                            int E)
{
    int e = blockIdx.x * blockDim.x + threadIdx.x;
    if (e < E) atomicAdd(&counts[dst[e]], 1);
}

__global__ __launch_bounds__(256) void scan_partial_kernel(
    const int* __restrict__ counts, int* __restrict__ blocksum, int N)
{
    __shared__ int red[256];
    const int t = threadIdx.x;
    const int base = blockIdx.x * 1024 + t * 4;
    int s = 0;
    if (base + 3 < N) {
        int4 q = *reinterpret_cast<const int4*>(counts + base);
        s = q.x + q.y + q.z + q.w;
    } else {
        for (int j = 0; j < 4; ++j)
            if (base + j < N) s += counts[base + j];
    }
    red[t] = s;
    __syncthreads();
    for (int off = 128; off > 0; off >>= 1) {
        if (t < off) red[t] += red[t + off];
        __syncthreads();
    }
    if (t == 0) blocksum[blockIdx.x] = red[0];
}

__global__ __launch_bounds__(256) void scan_partials_kernel(
    int* __restrict__ blocksum, int nblocks)
{
    __shared__ int part[256];
    const int t = threadIdx.x;
    int v = (t < nblocks) ? blocksum[t] : 0;
    part[t] = v;
    __syncthreads();
    for (int off = 1; off < 256; off <<= 1) {
        int tmp = (t >= off) ? part[t - off] : 0;
        __syncthreads();
        part[t] += tmp;
        __syncthreads();
    }
    if (t < nblocks) blocksum[t] = part[t] - v;  // exclusive
}

__global__ __launch_bounds__(256) void scan_block_kernel(
    const int* __restrict__ counts, const int* __restrict__ blocksum,
    int* __restrict__ offsets, int N, int nblocks)
{
    __shared__ int part[256];
    const int b = blockIdx.x, t = threadIdx.x;
    const int base = b * 1024 + t * 4;
    int v[4] = {0, 0, 0, 0};
    if (base + 3 < N) {
        int4 q = *reinterpret_cast<const int4*>(counts + base);
        v[0] = q.x; v[1] = q.y; v[2] = q.z; v[3] = q.w;
    } else {
        for (int j = 0; j < 4; ++j)
            if (base + j < N) v[j] = counts[base + j];
    }
    int s = v[0] + v[1] + v[2] + v[3];
    part[t] = s;
    __syncthreads();
    for (int off = 1; off < 256; off <<= 1) {
        int tmp = (t >= off) ? part[t - off] : 0;
        __syncthreads();
        part[t] += tmp;
        __syncthreads();
    }
    int excl = part[t] - s + blocksum[b];
    int o0 = excl, o1 = o0 + v[0], o2 = o1 + v[1], o3 = o2 + v[2];
    if (base + 3 < N) {
        *reinterpret_cast<int4*>(offsets + base) = make_int4(o0, o1, o2, o3);
    } else {
        int oo[4] = {o0, o1, o2, o3};
        for (int j = 0; j < 4; ++j)
            if (base + j < N) offsets[base + j] = oo[j];
    }
    if (b == nblocks - 1 && t == 255) offsets[N] = blocksum[b] + part[255];
}

__global__ void fill_kernel(const int* __restrict__ src, const int* __restrict__ dst,
                            const int* __restrict__ offsets, int* __restrict__ counts,
                            int* __restrict__ perm, int E)
{
    int e = blockIdx.x * blockDim.x + threadIdx.x;
    if (e >= E) return;
    int d = dst[e];
    int r = atomicSub(&counts[d], 1);  // old value in [1..deg]
    perm[offsets[d] + r - 1] = src[e];
}

// ---------------------------------------------------------------------------
// Gather-aggregate from bf16 table: x[row] = h_dst[row](f32) + sum h_src[perm].
// One wave per row (uniform row -> s_load of offsets/perm), 2 cols per lane,
// f32 accumulation, bf16 output.
// ---------------------------------------------------------------------------
__global__ __launch_bounds__(256) void gather_agg_kernel(
    const unsigned short* __restrict__ hb, const float* __restrict__ hdst,
    const int* __restrict__ offsets, const int* __restrict__ perm,
    unsigned short* __restrict__ x, int N)
{
    int row = blockIdx.x * 4 + (threadIdx.x >> 6);
    row = __builtin_amdgcn_readfirstlane(row);
    if (row >= N) return;
    const int c = (threadIdx.x & 63) * 2;
    const int beg = offsets[row], end = offsets[row + 1];
    float2 acc = *reinterpret_cast<const float2*>(hdst + (size_t)row * D + c);
    int i = beg;
    for (; i + 3 < end; i += 4) {
        int s0 = perm[i], s1 = perm[i + 1], s2 = perm[i + 2], s3 = perm[i + 3];
        unsigned u0 = *reinterpret_cast<const unsigned*>(hb + (size_t)s0 * D + c);
        unsigned u1 = *reinterpret_cast<const unsigned*>(hb + (size_t)s1 * D + c);
        unsigned u2 = *reinterpret_cast<const unsigned*>(hb + (size_t)s2 * D + c);
        unsigned u3 = *reinterpret_cast<const unsigned*>(hb + (size_t)s3 * D + c);
        acc.x += (bflo(u0) + bflo(u1)) + (bflo(u2) + bflo(u3));
        acc.y += (bfhi(u0) + bfhi(u1)) + (bfhi(u2) + bfhi(u3));
    }
    for (; i < end; ++i) {
        unsigned u = *reinterpret_cast<const unsigned*>(hb + (size_t)perm[i] * D + c);
        acc.x += bflo(u);
        acc.y += bfhi(u);
    }
    unsigned o = (unsigned)f2bf(acc.x) | ((unsigned)f2bf(acc.y) << 16);
    *reinterpret_cast<unsigned*>(x + (size_t)row * D + c) = o;
}

// ---------------------------------------------------------------------------
// bn+relu applied to bf16 u32 pair (2 elems), repacked to bf16.
// ---------------------------------------------------------------------------
__device__ __forceinline__ unsigned bnpack(unsigned u, float sLo, float sHi,
                                           float bLo, float bHi)
{
    float lo = fmaxf(fmaf(bflo(u), sLo, bLo), 0.f);
    float hi = fmaxf(fmaf(bfhi(u), sHi, bHi), 0.f);
    return (unsigned)f2bf(lo) | ((unsigned)f2bf(hi) << 16);
}

// ---------------------------------------------------------------------------
// MFMA GEMM: Y(bf16) = X(bf16) @ W, W held as Wt[n][k] bf16.
// Block = 4 waves; wave owns 16 rows x 128 cols; W fragments preloaded into
// 128 VGPRs (no LDS in the loop). Optional BN+ReLU fused into the A load.
// Per-column sum/sumsq accumulate in registers; block-reduced; one atomic set.
// mfma_f32_16x16x32_bf16: A row=l&15, k=(l>>4)*8+j ; D col=l&15, row=(l>>4)*4+j.
// ---------------------------------------------------------------------------
template <bool BN_IN>
__global__ __launch_bounds__(256, 2) void gemm_stats_kernel(
    const unsigned short* __restrict__ X, const unsigned short* __restrict__ Wt,
    const float* __restrict__ sc, const float* __restrict__ bi,
    unsigned short* __restrict__ Y, float* __restrict__ osum,
    float* __restrict__ osq, int N, int ntiles)
{
    const int t = threadIdx.x;
    const int w = t >> 6;
    const int l = t & 63;
    const int lr = l & 15;          // A row / D col within fragment
    const int lk = (l >> 4) << 3;   // k offset within 32-step

    // Preload all W fragments: frag(kk, n) = Wt[n*16+lr][kk*32+lk .. +8]
    uint4 wf[4][8];
#pragma unroll
    for (int kk = 0; kk < 4; ++kk)
#pragma unroll
        for (int n = 0; n < 8; ++n)
            wf[kk][n] = *reinterpret_cast<const uint4*>(
                Wt + (size_t)(n * 16 + lr) * D + kk * 32 + lk);

    float ps[8], pq[8];
#pragma unroll
    for (int n = 0; n < 8; ++n) { ps[n] = 0.f; pq[n] = 0.f; }

    for (int tile = blockIdx.x; tile < ntiles; tile += gridDim.x) {
        const int arow = tile * 64 + w * 16 + lr;
        f32x4 acc[8];
#pragma unroll
        for (int n = 0; n < 8; ++n) acc[n] = (f32x4){0.f, 0.f, 0.f, 0.f};

#pragma unroll
        for (int kk = 0; kk < 4; ++kk) {
            uint4 a4 = make_uint4(0u, 0u, 0u, 0u);
            if (arow < N) {
                a4 = *reinterpret_cast<const uint4*>(
                    X + (size_t)arow * D + kk * 32 + lk);
                if constexpr (BN_IN) {
                    const int kb = kk * 32 + lk;
                    float4 s0 = *reinterpret_cast<const float4*>(sc + kb);
                    float4 s1 = *reinterpret_cast<const float4*>(sc + kb + 4);
                    float4 b0 = *reinterpret_cast<const float4*>(bi + kb);
                    float4 b1 = *reinterpret_cast<const float4*>(bi + kb + 4);
                    a4.x = bnpack(a4.x, s0.x, s0.y, b0.x, b0.y);
                    a4.y = bnpack(a4.y, s0.z, s0.w, b0.z, b0.w);
                    a4.z = bnpack(a4.z, s1.x, s1.y, b1.x, b1.y);
                    a4.w = bnpack(a4.w, s1.z, s1.w, b1.z, b1.w);
                }
            }
            short8 a = __builtin_bit_cast(short8, a4);
#pragma unroll
            for (int n = 0; n < 8; ++n)
                acc[n] = __builtin_amdgcn_mfma_f32_16x16x32_bf16(
                    a, __builtin_bit_cast(short8, wf[kk][n]), acc[n], 0, 0, 0);
        }

        const int orow = tile * 64 + w * 16 + (l >> 4) * 4;
#pragma unroll
        for (int n = 0; n < 8; ++n) {
#pragma unroll
            for (int j = 0; j < 4; ++j) {
                float v = acc[n][j];
                ps[n] += v;          // pad rows produce exact 0 (A row zeroed)
                pq[n] += v * v;
                if (orow + j < N)
                    Y[(size_t)(orow + j) * D + n * 16 + lr] = f2bf(v);
            }
        }
    }

    // Cross-lane: reduce over the 4 row-groups (lanes l, l^16, l^32).
#pragma unroll
    for (int n = 0; n < 8; ++n) {
        ps[n] += __shfl_xor(ps[n], 16); ps[n] += __shfl_xor(ps[n], 32);
        pq[n] += __shfl_xor(pq[n], 16); pq[n] += __shfl_xor(pq[n], 32);
    }
    __shared__ float ssum[4][D], ssq[4][D];
    if (l < 16) {
#pragma unroll
        for (int n = 0; n < 8; ++n) {
            ssum[w][n * 16 + l] = ps[n];
            ssq[w][n * 16 + l]  = pq[n];
        }
    }
    __syncthreads();
    if (t < D) {
        float a = ssum[0][t] + ssum[1][t] + ssum[2][t] + ssum[3][t];
        float b = ssq[0][t] + ssq[1][t] + ssq[2][t] + ssq[3][t];
        atomicAdd(&osum[t], a);
        atomicAdd(&osq[t], b);
    }
}

// ---------------------------------------------------------------------------
__global__ void bn_finalize_kernel(const float* __restrict__ sum,
                                   const float* __restrict__ sq,
                                   const float* __restrict__ g,
                                   const float* __restrict__ b,
                                   float* __restrict__ sc,
                                   float* __restrict__ bi, int N)
{
    int c = threadIdx.x;
    float inv_n = 1.f / (float)N;
    float mean = sum[c] * inv_n;
    float var = fmaxf(sq[c] * inv_n - mean * mean, 0.f);
    float s = g[c] * rsqrtf(var + BN_EPS);
    sc[c] = s;
    bi[c] = b[c] - mean * s;
}

// ---------------------------------------------------------------------------
// out(f32) = relu(z(bf16)*scale + bias); work unit = 8 elems.
// ---------------------------------------------------------------------------
__global__ void bn_relu_out_kernel(const unsigned short* __restrict__ Z,
                                   const float* __restrict__ sc,
                                   const float* __restrict__ bi,
                                   float* __restrict__ out, int n8)
{
    for (int i = blockIdx.x * blockDim.x + threadIdx.x; i < n8;
         i += gridDim.x * blockDim.x) {
        uint4 z = reinterpret_cast<const uint4*>(Z)[i];
        int c = (i * 8) & (D - 1);
        float4 s0 = *reinterpret_cast<const float4*>(sc + c);
        float4 s1 = *reinterpret_cast<const float4*>(sc + c + 4);
        float4 b0 = *reinterpret_cast<const float4*>(bi + c);
        float4 b1 = *reinterpret_cast<const float4*>(bi + c + 4);
        float4 o0, o1;
        o0.x = fmaxf(fmaf(bflo(z.x), s0.x, b0.x), 0.f);
        o0.y = fmaxf(fmaf(bfhi(z.x), s0.y, b0.y), 0.f);
        o0.z = fmaxf(fmaf(bflo(z.y), s0.z, b0.z), 0.f);
        o0.w = fmaxf(fmaf(bfhi(z.y), s0.w, b0.w), 0.f);
        o1.x = fmaxf(fmaf(bflo(z.z), s1.x, b1.x), 0.f);
        o1.y = fmaxf(fmaf(bfhi(z.z), s1.y, b1.y), 0.f);
        o1.z = fmaxf(fmaf(bflo(z.w), s1.z, b1.z), 0.f);
        o1.w = fmaxf(fmaf(bfhi(z.w), s1.w, b1.w), 0.f);
        reinterpret_cast<float4*>(out)[i * 2] = o0;
        reinterpret_cast<float4*>(out)[i * 2 + 1] = o1;
    }
}

// ---------------------------------------------------------------------------
extern "C" void kernel_launch(void* const* d_in, const int* in_sizes, int n_in,
                              void* d_out, int out_size, void* d_ws, size_t ws_size,
                              hipStream_t stream)
{
    const float* h_user   = (const float*)d_in[0];
    const float* h_item   = (const float*)d_in[1];
    const int* src_rates  = (const int*)d_in[2];
    const int* dst_rates  = (const int*)d_in[3];
    const int* src_rev    = (const int*)d_in[4];
    const int* dst_rev    = (const int*)d_in[5];
    const float* W1_rates = (const float*)d_in[6];
    const float* W2_rates = (const float*)d_in[7];
    const float* g1_rates = (const float*)d_in[8];
    const float* b1_rates = (const float*)d_in[9];
    const float* g2_rates = (const float*)d_in[10];
    const float* b2_rates = (const float*)d_in[11];
    const float* W1_rev   = (const float*)d_in[12];
    const float* W2_rev   = (const float*)d_in[13];
    const float* g1_rev   = (const float*)d_in[14];
    const float* b1_rev   = (const float*)d_in[15];
    const float* g2_rev   = (const float*)d_in[16];
    const float* b2_rev   = (const float*)d_in[17];

    const int n_user = in_sizes[0] / D;
    const int n_item = in_sizes[1] / D;
    const int E1 = in_sizes[2];
    const int E2 = in_sizes[4];
    const int n_max = n_user > n_item ? n_user : n_item;
    const int e_max = E1 > E2 ? E1 : E2;

    // Workspace layout (bytes, 256-aligned slices)
    char* p = (char*)d_ws;
    auto alloc = [&](size_t bytes) {
        char* q = p;
        p += (bytes + 255) & ~(size_t)255;
        return q;
    };
    unsigned short* hbu = (unsigned short*)alloc((size_t)n_user * D * 2);
    unsigned short* hbi = (unsigned short*)alloc((size_t)n_item * D * 2);
    unsigned short* xz  = (unsigned short*)alloc((size_t)n_max * D * 2);
    unsigned short* yb  = (unsigned short*)alloc((size_t)n_max * D * 2);
    unsigned short* wt  = (unsigned short*)alloc((size_t)4 * D * D * 2);
    float* stats  = (float*)alloc((size_t)16 * D * 4);
    int* counts   = (int*)alloc((size_t)n_max * 4);
    int* offsets  = (int*)alloc(((size_t)n_max + 1) * 4);
    int* blocksum = (int*)alloc((size_t)256 * 4);
    int* perm     = (int*)alloc((size_t)e_max * 4);

    float* out_user = (float*)d_out;
    float* out_item = out_user + (size_t)n_user * D;

    // Upfront: bf16 tables + transposed bf16 weights + zero stats.
    const int nu8 = n_user * D / 8, ni8 = n_item * D / 8;
    convert_h_kernel<<<(nu8 + ni8 + 255) / 256, 256, 0, stream>>>(
        h_user, h_item, hbu, hbi, nu8, ni8);
    prep_w_kernel<<<64, 256, 0, stream>>>(W1_rates, W2_rates, W1_rev, W2_rev, wt);
    hipMemsetAsync(stats, 0, 16 * D * sizeof(float), stream);

    auto run_rel = [&](const unsigned short* hsrc_b, const float* hdst,
                       const int* src, const int* dst, int E, int Ndst,
                       const unsigned short* wt1, const unsigned short* wt2,
                       const float* g1, const float* b1, const float* g2,
                       const float* b2, float* out, float* st) {
        int eblocks = (E + 255) / 256;
        int nscan = (Ndst + 1023) / 1024;  // <= 256

        // --- CSR build ---
        hipMemsetAsync(counts, 0, (size_t)Ndst * sizeof(int), stream);
        hist_kernel<<<eblocks, 256, 0, stream>>>(dst, counts, E);
        scan_partial_kernel<<<nscan, 256, 0, stream>>>(counts, blocksum, Ndst);
        scan_partials_kernel<<<1, 256, 0, stream>>>(blocksum, nscan);
        scan_block_kernel<<<nscan, 256, 0, stream>>>(counts, blocksum, offsets,
                                                     Ndst, nscan);
        fill_kernel<<<eblocks, 256, 0, stream>>>(src, dst, offsets, counts, perm, E);

        // --- x = h_dst + segment_sum(h_src[perm])  (bf16 out) ---
        gather_agg_kernel<<<(Ndst + 3) / 4, 256, 0, stream>>>(
            hsrc_b, hdst, offsets, perm, xz, Ndst);

        float* sum1 = st;         float* sq1 = st + D;
        float* sc1  = st + 2 * D; float* bi1 = st + 3 * D;
        float* sum2 = st + 4 * D; float* sq2 = st + 5 * D;
        float* sc2  = st + 6 * D; float* bi2 = st + 7 * D;

        int ntiles = (Ndst + 63) / 64;
        int gblocks = ntiles < 512 ? ntiles : 512;
        gemm_stats_kernel<false><<<gblocks, 256, 0, stream>>>(
            xz, wt1, nullptr, nullptr, yb, sum1, sq1, Ndst, ntiles);
        bn_finalize_kernel<<<1, D, 0, stream>>>(sum1, sq1, g1, b1, sc1, bi1, Ndst);
        gemm_stats_kernel<true><<<gblocks, 256, 0, stream>>>(
            yb, wt2, sc1, bi1, xz, sum2, sq2, Ndst, ntiles);
        bn_finalize_kernel<<<1, D, 0, stream>>>(sum2, sq2, g2, b2, sc2, bi2, Ndst);

        int n8 = Ndst * (D / 8);
        int oblocks = (n8 + 255) / 256;
        if (oblocks > 2048) oblocks = 2048;
        bn_relu_out_kernel<<<oblocks, 256, 0, stream>>>(xz, sc2, bi2, out, n8);
    };

    // relation 'rates': user -> item  => out_item
    run_rel(hbu, h_item, src_rates, dst_rates, E1, n_item,
            wt, wt + D * D, g1_rates, b1_rates, g2_rates, b2_rates,
            out_item, stats);
    // relation 'rated_by': item -> user => out_user
    run_rel(hbi, h_user, src_rev, dst_rev, E2, n_user,
            wt + 2 * D * D, wt + 3 * D * D, g1_rev, b1_rev, g2_rev, b2_rev,
            out_user, stats + 8 * D);
}

// Round 6
// 269.915 us; speedup vs baseline: 9.0138x; 1.2875x over previous
//
#include <hip/hip_runtime.h>

#define D 128
static constexpr float BN_EPS = 1e-5f;

typedef __attribute__((ext_vector_type(8))) short short8;
typedef __attribute__((ext_vector_type(4))) float f32x4;

// ---------------------------------------------------------------------------
// bf16 helpers (RNE)
// ---------------------------------------------------------------------------
__device__ __forceinline__ unsigned short f2bf(float f)
{
    unsigned u = __builtin_bit_cast(unsigned, f);
    unsigned r = u + 0x7fffu + ((u >> 16) & 1u);
    return (unsigned short)(r >> 16);
}
__device__ __forceinline__ float bflo(unsigned u)
{
    return __builtin_bit_cast(float, u << 16);
}
__device__ __forceinline__ float bfhi(unsigned u)
{
    return __builtin_bit_cast(float, u & 0xffff0000u);
}

// ---------------------------------------------------------------------------
// Per-relation parameter bundles (passed by value; blockIdx.y selects).
// ---------------------------------------------------------------------------
struct CsrRel {
    const int* src; const int* dst;
    int* counts; int* offsets; int* bsum; int* perm;
    int E; int N; int nscan;
};
struct GatherRel {
    const unsigned short* hb; const float* hdst;
    const int* offsets; const int* perm;
    unsigned short* x; int N;
};
struct GemmRel {
    const unsigned short* X; const unsigned short* Wt;
    const float* insum; const float* insq; const float* gg; const float* bb;
    unsigned short* Y; float* osum; float* osq;
    int N; int ntiles;
};
struct OutRel {
    const unsigned short* z;
    const float* sum; const float* sq; const float* gg; const float* bb;
    float* out; int N;
};

// ---------------------------------------------------------------------------
// h (f32) -> bf16 tables, both node types in one kernel. Work unit = 8 elems.
// ---------------------------------------------------------------------------
__global__ void convert_h_kernel(const float* __restrict__ hu,
                                 const float* __restrict__ hi,
                                 unsigned short* __restrict__ bu,
                                 unsigned short* __restrict__ bi8,
                                 int nu8, int ni8)
{
    int i = blockIdx.x * blockDim.x + threadIdx.x;
    if (i >= nu8 + ni8) return;
    const float* s; unsigned short* d; int o;
    if (i < nu8) { s = hu; d = bu; o = i; }
    else         { s = hi; d = bi8; o = i - nu8; }
    float4 v0 = reinterpret_cast<const float4*>(s)[o * 2];
    float4 v1 = reinterpret_cast<const float4*>(s)[o * 2 + 1];
    uint4 r;
    r.x = (unsigned)f2bf(v0.x) | ((unsigned)f2bf(v0.y) << 16);
    r.y = (unsigned)f2bf(v0.z) | ((unsigned)f2bf(v0.w) << 16);
    r.z = (unsigned)f2bf(v1.x) | ((unsigned)f2bf(v1.y) << 16);
    r.w = (unsigned)f2bf(v1.z) | ((unsigned)f2bf(v1.w) << 16);
    reinterpret_cast<uint4*>(d)[o] = r;
}

// ---------------------------------------------------------------------------
// W [k][n] f32 -> Wt [n][k] bf16 for the 4 weight matrices. 64 blocks.
// ---------------------------------------------------------------------------
__global__ __launch_bounds__(256) void prep_w_kernel(
    const float* __restrict__ Wa, const float* __restrict__ Wb,
    const float* __restrict__ Wc, const float* __restrict__ Wd,
    unsigned short* __restrict__ wt)
{
    const int wsel = blockIdx.x >> 4;
    const float* W = wsel == 0 ? Wa : wsel == 1 ? Wb : wsel == 2 ? Wc : Wd;
    unsigned short* out = wt + (size_t)wsel * D * D;
    const int tile = blockIdx.x & 15;
    const int k0 = (tile >> 2) * 32, n0 = (tile & 3) * 32;
    __shared__ float s[32][33];
    const int t = threadIdx.x;
    const int r = t >> 3, c = (t & 7) * 4;
    float4 v = *reinterpret_cast<const float4*>(W + (size_t)(k0 + r) * D + n0 + c);
    s[r][c] = v.x; s[r][c + 1] = v.y; s[r][c + 2] = v.z; s[r][c + 3] = v.w;
    __syncthreads();
    unsigned lo = (unsigned)f2bf(s[c][r]) | ((unsigned)f2bf(s[c + 1][r]) << 16);
    unsigned hi = (unsigned)f2bf(s[c + 2][r]) | ((unsigned)f2bf(s[c + 3][r]) << 16);
    *reinterpret_cast<uint2*>(out + (size_t)(n0 + r) * D + k0 + c) =
        make_uint2(lo, hi);
}

// ---------------------------------------------------------------------------
// CSR build, both relations per dispatch (blockIdx.y).
// ---------------------------------------------------------------------------
__global__ void hist_kernel(CsrRel r0, CsrRel r1)
{
    CsrRel r = blockIdx.y ? r1 : r0;
    int e = blockIdx.x * blockDim.x + threadIdx.x;
    if (e < r.E) atomicAdd(&r.counts[r.dst[e]], 1);
}

__global__ __launch_bounds__(256) void scan_partial_kernel(CsrRel rr0, CsrRel rr1)
{
    CsrRel r = blockIdx.y ? rr1 : rr0;
    if ((int)blockIdx.x >= r.nscan) return;
    __shared__ int red[256];
    const int t = threadIdx.x;
    const int base = blockIdx.x * 1024 + t * 4;
    int s = 0;
    if (base + 3 < r.N) {
        int4 q = *reinterpret_cast<const int4*>(r.counts + base);
        s = q.x + q.y + q.z + q.w;
    } else {
        for (int j = 0; j < 4; ++j)
            if (base + j < r.N) s += r.counts[base + j];
    }
    red[t] = s;
    __syncthreads();
    for (int off = 128; off > 0; off >>= 1) {
        if (t < off) red[t] += red[t + off];
        __syncthreads();
    }
    if (t == 0) r.bsum[blockIdx.x] = red[0];
}

__global__ __launch_bounds__(256) void scan_partials_kernel(CsrRel rr0, CsrRel rr1)
{
    CsrRel r = blockIdx.y ? rr1 : rr0;
    __shared__ int part[256];
    const int t = threadIdx.x;
    int v = (t < r.nscan) ? r.bsum[t] : 0;
    part[t] = v;
    __syncthreads();
    for (int off = 1; off < 256; off <<= 1) {
        int tmp = (t >= off) ? part[t - off] : 0;
        __syncthreads();
        part[t] += tmp;
        __syncthreads();
    }
    if (t < r.nscan) r.bsum[t] = part[t] - v;  // exclusive
}

__global__ __launch_bounds__(256) void scan_block_kernel(CsrRel rr0, CsrRel rr1)
{
    CsrRel r = blockIdx.y ? rr1 : rr0;
    if ((int)blockIdx.x >= r.nscan) return;
    __shared__ int part[256];
    const int b = blockIdx.x, t = threadIdx.x;
    const int base = b * 1024 + t * 4;
    int v[4] = {0, 0, 0, 0};
    if (base + 3 < r.N) {
        int4 q = *reinterpret_cast<const int4*>(r.counts + base);
        v[0] = q.x; v[1] = q.y; v[2] = q.z; v[3] = q.w;
    } else {
        for (int j = 0; j < 4; ++j)
            if (base + j < r.N) v[j] = r.counts[base + j];
    }
    int s = v[0] + v[1] + v[2] + v[3];
    part[t] = s;
    __syncthreads();
    for (int off = 1; off < 256; off <<= 1) {
        int tmp = (t >= off) ? part[t - off] : 0;
        __syncthreads();
        part[t] += tmp;
        __syncthreads();
    }
    int excl = part[t] - s + r.bsum[b];
    int o0 = excl, o1 = o0 + v[0], o2 = o1 + v[1], o3 = o2 + v[2];
    if (base + 3 < r.N) {
        *reinterpret_cast<int4*>(r.offsets + base) = make_int4(o0, o1, o2, o3);
    } else {
        int oo[4] = {o0, o1, o2, o3};
        for (int j = 0; j < 4; ++j)
            if (base + j < r.N) r.offsets[base + j] = oo[j];
    }
    if (b == r.nscan - 1 && t == 255) r.offsets[r.N] = r.bsum[b] + part[255];
}

__global__ void fill_kernel(CsrRel rr0, CsrRel rr1)
{
    CsrRel r = blockIdx.y ? rr1 : rr0;
    int e = blockIdx.x * blockDim.x + threadIdx.x;
    if (e >= r.E) return;
    int d = r.dst[e];
    int c = atomicSub(&r.counts[d], 1);  // old value in [1..deg]; ends at 0
    r.perm[r.offsets[d] + c - 1] = r.src[e];
}

// ---------------------------------------------------------------------------
// Gather-aggregate from bf16 table: x[row] = h_dst[row](f32) + sum h_src[perm].
// One wave per row, 2 cols per lane, f32 accumulation, bf16 output.
// ---------------------------------------------------------------------------
__global__ __launch_bounds__(256) void gather_agg_kernel(GatherRel g0, GatherRel g1)
{
    GatherRel g = blockIdx.y ? g1 : g0;
    int row = blockIdx.x * 4 + (threadIdx.x >> 6);
    row = __builtin_amdgcn_readfirstlane(row);
    if (row >= g.N) return;
    const int c = (threadIdx.x & 63) * 2;
    const int beg = g.offsets[row], end = g.offsets[row + 1];
    float2 acc = *reinterpret_cast<const float2*>(g.hdst + (size_t)row * D + c);
    const unsigned short* hb = g.hb;
    int i = beg;
    for (; i + 3 < end; i += 4) {
        int s0 = g.perm[i], s1 = g.perm[i + 1];
        int s2 = g.perm[i + 2], s3 = g.perm[i + 3];
        unsigned u0 = *reinterpret_cast<const unsigned*>(hb + (size_t)s0 * D + c);
        unsigned u1 = *reinterpret_cast<const unsigned*>(hb + (size_t)s1 * D + c);
        unsigned u2 = *reinterpret_cast<const unsigned*>(hb + (size_t)s2 * D + c);
        unsigned u3 = *reinterpret_cast<const unsigned*>(hb + (size_t)s3 * D + c);
        acc.x += (bflo(u0) + bflo(u1)) + (bflo(u2) + bflo(u3));
        acc.y += (bfhi(u0) + bfhi(u1)) + (bfhi(u2) + bfhi(u3));
    }
    for (; i < end; ++i) {
        unsigned u = *reinterpret_cast<const unsigned*>(hb + (size_t)g.perm[i] * D + c);
        acc.x += bflo(u);
        acc.y += bfhi(u);
    }
    unsigned o = (unsigned)f2bf(acc.x) | ((unsigned)f2bf(acc.y) << 16);
    *reinterpret_cast<unsigned*>(g.x + (size_t)row * D + c) = o;
}

// ---------------------------------------------------------------------------
// bn+relu applied to bf16 u32 pair (2 elems), repacked to bf16.
// ---------------------------------------------------------------------------
__device__ __forceinline__ unsigned bnpack(unsigned u, float sLo, float sHi,
                                           float bLo, float bHi)
{
    float lo = fmaxf(fmaf(bflo(u), sLo, bLo), 0.f);
    float hi = fmaxf(fmaf(bfhi(u), sHi, bHi), 0.f);
    return (unsigned)f2bf(lo) | ((unsigned)f2bf(hi) << 16);
}

// ---------------------------------------------------------------------------
// MFMA GEMM: Y(bf16) = X(bf16) @ W, W as Wt[n][k] bf16 preloaded into VGPRs.
// If BN_IN: per-block prologue computes scale/bias from (insum,insq,g,b) into
// LDS (replaces the separate bn_finalize launch), applied to A on load.
// Per-column sum/sumsq of Y accumulate in registers; one atomic set per block.
// ---------------------------------------------------------------------------
template <bool BN_IN>
__global__ __launch_bounds__(256, 2) void gemm_stats_kernel(GemmRel q0, GemmRel q1)
{
    GemmRel q = blockIdx.y ? q1 : q0;
    const int t = threadIdx.x;
    const int w = t >> 6;
    const int l = t & 63;
    const int lr = l & 15;          // A row / D col within fragment
    const int lk = (l >> 4) << 3;   // k offset within 32-step

    __shared__ float s_sc[D], s_bi[D];
    if constexpr (BN_IN) {
        if (t < D) {
            float inv_n = 1.f / (float)q.N;
            float mean = q.insum[t] * inv_n;
            float var = fmaxf(q.insq[t] * inv_n - mean * mean, 0.f);
            float s = q.gg[t] * rsqrtf(var + BN_EPS);
            s_sc[t] = s;
            s_bi[t] = q.bb[t] - mean * s;
        }
        __syncthreads();
    }

    // Preload all W fragments: frag(kk, n) = Wt[n*16+lr][kk*32+lk .. +8]
    uint4 wf[4][8];
#pragma unroll
    for (int kk = 0; kk < 4; ++kk)
#pragma unroll
        for (int n = 0; n < 8; ++n)
            wf[kk][n] = *reinterpret_cast<const uint4*>(
                q.Wt + (size_t)(n * 16 + lr) * D + kk * 32 + lk);

    float ps[8], pq[8];
#pragma unroll
    for (int n = 0; n < 8; ++n) { ps[n] = 0.f; pq[n] = 0.f; }

    for (int tile = blockIdx.x; tile < q.ntiles; tile += gridDim.x) {
        const int arow = tile * 64 + w * 16 + lr;
        f32x4 acc[8];
#pragma unroll
        for (int n = 0; n < 8; ++n) acc[n] = (f32x4){0.f, 0.f, 0.f, 0.f};

#pragma unroll
        for (int kk = 0; kk < 4; ++kk) {
            uint4 a4 = make_uint4(0u, 0u, 0u, 0u);
            if (arow < q.N) {
                a4 = *reinterpret_cast<const uint4*>(
                    q.X + (size_t)arow * D + kk * 32 + lk);
                if constexpr (BN_IN) {
                    const int kb = kk * 32 + lk;
                    float4 s0 = *reinterpret_cast<const float4*>(&s_sc[kb]);
                    float4 s1 = *reinterpret_cast<const float4*>(&s_sc[kb + 4]);
                    float4 b0 = *reinterpret_cast<const float4*>(&s_bi[kb]);
                    float4 b1 = *reinterpret_cast<const float4*>(&s_bi[kb + 4]);
                    a4.x = bnpack(a4.x, s0.x, s0.y, b0.x, b0.y);
                    a4.y = bnpack(a4.y, s0.z, s0.w, b0.z, b0.w);
                    a4.z = bnpack(a4.z, s1.x, s1.y, b1.x, b1.y);
                    a4.w = bnpack(a4.w, s1.z, s1.w, b1.z, b1.w);
                }
            }
            short8 a = __builtin_bit_cast(short8, a4);
#pragma unroll
            for (int n = 0; n < 8; ++n)
                acc[n] = __builtin_amdgcn_mfma_f32_16x16x32_bf16(
                    a, __builtin_bit_cast(short8, wf[kk][n]), acc[n], 0, 0, 0);
        }

        const int orow = tile * 64 + w * 16 + (l >> 4) * 4;
#pragma unroll
        for (int n = 0; n < 8; ++n) {
#pragma unroll
            for (int j = 0; j < 4; ++j) {
                float v = acc[n][j];
                ps[n] += v;          // pad rows produce exact 0 (A row zeroed)
                pq[n] += v * v;
                if (orow + j < q.N)
                    q.Y[(size_t)(orow + j) * D + n * 16 + lr] = f2bf(v);
            }
        }
    }

    // Cross-lane: reduce over the 4 row-groups (lanes l, l^16, l^32).
#pragma unroll
    for (int n = 0; n < 8; ++n) {
        ps[n] += __shfl_xor(ps[n], 16); ps[n] += __shfl_xor(ps[n], 32);
        pq[n] += __shfl_xor(pq[n], 16); pq[n] += __shfl_xor(pq[n], 32);
    }
    __shared__ float ssum[4][D], ssq[4][D];
    if (l < 16) {
#pragma unroll
        for (int n = 0; n < 8; ++n) {
            ssum[w][n * 16 + l] = ps[n];
            ssq[w][n * 16 + l]  = pq[n];
        }
    }
    __syncthreads();
    if (t < D) {
        float a = ssum[0][t] + ssum[1][t] + ssum[2][t] + ssum[3][t];
        float b = ssq[0][t] + ssq[1][t] + ssq[2][t] + ssq[3][t];
        atomicAdd(&q.osum[t], a);
        atomicAdd(&q.osq[t], b);
    }
}

// ---------------------------------------------------------------------------
// out(f32) = relu(bn(z bf16)); BN finalize computed per block from raw sums.
// ---------------------------------------------------------------------------
__global__ __launch_bounds__(256) void bn_relu_out_kernel(OutRel o0, OutRel o1)
{
    OutRel o = blockIdx.y ? o1 : o0;
    __shared__ float s_sc[D], s_bi[D];
    if (threadIdx.x < D) {
        int c = threadIdx.x;
        float inv_n = 1.f / (float)o.N;
        float mean = o.sum[c] * inv_n;
        float var = fmaxf(o.sq[c] * inv_n - mean * mean, 0.f);
        float s = o.gg[c] * rsqrtf(var + BN_EPS);
        s_sc[c] = s;
        s_bi[c] = o.bb[c] - mean * s;
    }
    __syncthreads();

    const int n8 = o.N * (D / 8);
    for (int i = blockIdx.x * blockDim.x + threadIdx.x; i < n8;
         i += gridDim.x * blockDim.x) {
        uint4 z = reinterpret_cast<const uint4*>(o.z)[i];
        int c = (i * 8) & (D - 1);
        float4 s0 = *reinterpret_cast<const float4*>(&s_sc[c]);
        float4 s1 = *reinterpret_cast<const float4*>(&s_sc[c + 4]);
        float4 b0 = *reinterpret_cast<const float4*>(&s_bi[c]);
        float4 b1 = *reinterpret_cast<const float4*>(&s_bi[c + 4]);
        float4 r0, r1;
        r0.x = fmaxf(fmaf(bflo(z.x), s0.x, b0.x), 0.f);
        r0.y = fmaxf(fmaf(bfhi(z.x), s0.y, b0.y), 0.f);
        r0.z = fmaxf(fmaf(bflo(z.y), s0.z, b0.z), 0.f);
        r0.w = fmaxf(fmaf(bfhi(z.y), s0.w, b0.w), 0.f);
        r1.x = fmaxf(fmaf(bflo(z.z), s1.x, b1.x), 0.f);
        r1.y = fmaxf(fmaf(bfhi(z.z), s1.y, b1.y), 0.f);
        r1.z = fmaxf(fmaf(bflo(z.w), s1.z, b1.z), 0.f);
        r1.w = fmaxf(fmaf(bfhi(z.w), s1.w, b1.w), 0.f);
        reinterpret_cast<float4*>(o.out)[i * 2] = r0;
        reinterpret_cast<float4*>(o.out)[i * 2 + 1] = r1;
    }
}

// ---------------------------------------------------------------------------
extern "C" void kernel_launch(void* const* d_in, const int* in_sizes, int n_in,
                              void* d_out, int out_size, void* d_ws, size_t ws_size,
                              hipStream_t stream)
{
    const float* h_user   = (const float*)d_in[0];
    const float* h_item   = (const float*)d_in[1];
    const int* src_rates  = (const int*)d_in[2];
    const int* dst_rates  = (const int*)d_in[3];
    const int* src_rev    = (const int*)d_in[4];
    const int* dst_rev    = (const int*)d_in[5];
    const float* W1_rates = (const float*)d_in[6];
    const float* W2_rates = (const float*)d_in[7];
    const float* g1_rates = (const float*)d_in[8];
    const float* b1_rates = (const float*)d_in[9];
    const float* g2_rates = (const float*)d_in[10];
    const float* b2_rates = (const float*)d_in[11];
    const float* W1_rev   = (const float*)d_in[12];
    const float* W2_rev   = (const float*)d_in[13];
    const float* g1_rev   = (const float*)d_in[14];
    const float* b1_rev   = (const float*)d_in[15];
    const float* g2_rev   = (const float*)d_in[16];
    const float* b2_rev   = (const float*)d_in[17];

    const int n_user = in_sizes[0] / D;
    const int n_item = in_sizes[1] / D;
    const int E1 = in_sizes[2];
    const int E2 = in_sizes[4];

    // Workspace layout (256-aligned slices); zero-region = [stats .. counts1).
    char* p = (char*)d_ws;
    auto alloc = [&](size_t bytes) {
        char* q = p;
        p += (bytes + 255) & ~(size_t)255;
        return q;
    };
    unsigned short* hbu = (unsigned short*)alloc((size_t)n_user * D * 2);
    unsigned short* hbi = (unsigned short*)alloc((size_t)n_item * D * 2);
    unsigned short* xz0 = (unsigned short*)alloc((size_t)n_item * D * 2);
    unsigned short* xz1 = (unsigned short*)alloc((size_t)n_user * D * 2);
    unsigned short* yb0 = (unsigned short*)alloc((size_t)n_item * D * 2);
    unsigned short* yb1 = (unsigned short*)alloc((size_t)n_user * D * 2);
    unsigned short* wt  = (unsigned short*)alloc((size_t)4 * D * D * 2);
    char* zbeg = p;
    float* stats   = (float*)alloc((size_t)8 * D * 4);   // 2 rel x 4 arrays x D
    int* counts0   = (int*)alloc((size_t)n_item * 4);
    int* counts1   = (int*)alloc((size_t)n_user * 4);
    size_t zbytes  = (size_t)(p - zbeg);
    int* offsets0  = (int*)alloc(((size_t)n_item + 1) * 4);
    int* offsets1  = (int*)alloc(((size_t)n_user + 1) * 4);
    int* bsum0     = (int*)alloc((size_t)256 * 4);
    int* bsum1     = (int*)alloc((size_t)256 * 4);
    int* perm0     = (int*)alloc((size_t)E1 * 4);
    int* perm1     = (int*)alloc((size_t)E2 * 4);

    float* out_user = (float*)d_out;
    float* out_item = out_user + (size_t)n_user * D;

    // Upfront: bf16 tables, transposed bf16 weights, zero stats+counts.
    const int nu8 = n_user * D / 8, ni8 = n_item * D / 8;
    convert_h_kernel<<<(nu8 + ni8 + 255) / 256, 256, 0, stream>>>(
        h_user, h_item, hbu, hbi, nu8, ni8);
    prep_w_kernel<<<64, 256, 0, stream>>>(W1_rates, W2_rates, W1_rev, W2_rev, wt);
    hipMemsetAsync(zbeg, 0, zbytes, stream);

    // Per-relation stat slices: [sum1, sq1, sum2, sq2] x D
    float* st0 = stats;
    float* st1 = stats + 4 * D;

    // rel0 ('rates'): user -> item, out_item. rel1 ('rated_by'): item -> user.
    CsrRel c0 = {src_rates, dst_rates, counts0, offsets0, bsum0, perm0,
                 E1, n_item, (n_item + 1023) / 1024};
    CsrRel c1 = {src_rev, dst_rev, counts1, offsets1, bsum1, perm1,
                 E2, n_user, (n_user + 1023) / 1024};

    int eb = ((E1 > E2 ? E1 : E2) + 255) / 256;
    int ns = c0.nscan > c1.nscan ? c0.nscan : c1.nscan;
    hist_kernel<<<dim3(eb, 2), 256, 0, stream>>>(c0, c1);
    scan_partial_kernel<<<dim3(ns, 2), 256, 0, stream>>>(c0, c1);
    scan_partials_kernel<<<dim3(1, 2), 256, 0, stream>>>(c0, c1);
    scan_block_kernel<<<dim3(ns, 2), 256, 0, stream>>>(c0, c1);
    fill_kernel<<<dim3(eb, 2), 256, 0, stream>>>(c0, c1);

    GatherRel ga0 = {hbu, h_item, offsets0, perm0, xz0, n_item};
    GatherRel ga1 = {hbi, h_user, offsets1, perm1, xz1, n_user};
    int ab = ((n_item > n_user ? n_item : n_user) + 3) / 4;
    gather_agg_kernel<<<dim3(ab, 2), 256, 0, stream>>>(ga0, ga1);

    const int nt0 = (n_item + 63) / 64, nt1 = (n_user + 63) / 64;
    int gx = nt0 > nt1 ? nt0 : nt1;
    if (gx > 256) gx = 256;   // 512 total blocks = 2/CU capacity

    // GEMM1: y = x @ W1, stats of y.
    GemmRel q10 = {xz0, wt,             nullptr, nullptr, nullptr, nullptr,
                   yb0, st0, st0 + D, n_item, nt0};
    GemmRel q11 = {xz1, wt + 2 * D * D, nullptr, nullptr, nullptr, nullptr,
                   yb1, st1, st1 + D, n_user, nt1};
    gemm_stats_kernel<false><<<dim3(gx, 2), 256, 0, stream>>>(q10, q11);

    // GEMM2: z = relu(bn1(y)) @ W2 (bn1 finalized in-kernel), stats of z.
    GemmRel q20 = {yb0, wt + D * D,     st0, st0 + D, g1_rates, b1_rates,
                   xz0, st0 + 2 * D, st0 + 3 * D, n_item, nt0};
    GemmRel q21 = {yb1, wt + 3 * D * D, st1, st1 + D, g1_rev, b1_rev,
                   xz1, st1 + 2 * D, st1 + 3 * D, n_user, nt1};
    gemm_stats_kernel<true><<<dim3(gx, 2), 256, 0, stream>>>(q20, q21);

    // out = relu(bn2(z)) (bn2 finalized in-kernel).
    OutRel o0 = {xz0, st0 + 2 * D, st0 + 3 * D, g2_rates, b2_rates,
                 out_item, n_item};
    OutRel o1 = {xz1, st1 + 2 * D, st1 + 3 * D, g2_rev, b2_rev,
                 out_user, n_user};
    int n8m = (n_item > n_user ? n_item : n_user) * (D / 8);
    int ob = (n8m + 255) / 256;
    if (ob > 2048) ob = 2048;
    bn_relu_out_kernel<<<dim3(ob, 2), 256, 0, stream>>>(o0, o1);
}

// Round 7
// 223.675 us; speedup vs baseline: 10.8772x; 1.2067x over previous
//
#include <hip/hip_runtime.h>

#define D 128
static constexpr float BN_EPS = 1e-5f;

typedef __attribute__((ext_vector_type(8))) short short8;
typedef __attribute__((ext_vector_type(4))) float f32x4;

// ---------------------------------------------------------------------------
// bf16 helpers (RNE)
// ---------------------------------------------------------------------------
__device__ __forceinline__ unsigned short f2bf(float f)
{
    unsigned u = __builtin_bit_cast(unsigned, f);
    unsigned r = u + 0x7fffu + ((u >> 16) & 1u);
    return (unsigned short)(r >> 16);
}
__device__ __forceinline__ float bflo(unsigned u)
{
    return __builtin_bit_cast(float, u << 16);
}
__device__ __forceinline__ float bfhi(unsigned u)
{
    return __builtin_bit_cast(float, u & 0xffff0000u);
}

// ---------------------------------------------------------------------------
// Per-relation parameter bundles (passed by value; blockIdx.y selects).
// ---------------------------------------------------------------------------
struct CsrRel {
    const int* src; const int* dst;
    int* counts; int* offsets; int* bsum; int* perm; int* rank;
    int E; int N; int nscan;
};
struct GatherRel {
    const unsigned short* hb; const float* hdst;
    const int* offsets; const int* perm;
    unsigned short* x; int N;
};
struct GemmRel {
    const unsigned short* X; const unsigned short* Wt;
    const float* insum; const float* insq; const float* gg; const float* bb;
    unsigned short* Y; float* osum; float* osq;
    int N; int ntiles;
};
struct OutRel {
    const unsigned short* z;
    const float* sum; const float* sq; const float* gg; const float* bb;
    float* out; int N;
};

// ---------------------------------------------------------------------------
// h (f32) -> bf16 tables, both node types in one kernel. Work unit = 8 elems.
// ---------------------------------------------------------------------------
__global__ void convert_h_kernel(const float* __restrict__ hu,
                                 const float* __restrict__ hi,
                                 unsigned short* __restrict__ bu,
                                 unsigned short* __restrict__ bi8,
                                 int nu8, int ni8)
{
    int i = blockIdx.x * blockDim.x + threadIdx.x;
    if (i >= nu8 + ni8) return;
    const float* s; unsigned short* d; int o;
    if (i < nu8) { s = hu; d = bu; o = i; }
    else         { s = hi; d = bi8; o = i - nu8; }
    float4 v0 = reinterpret_cast<const float4*>(s)[o * 2];
    float4 v1 = reinterpret_cast<const float4*>(s)[o * 2 + 1];
    uint4 r;
    r.x = (unsigned)f2bf(v0.x) | ((unsigned)f2bf(v0.y) << 16);
    r.y = (unsigned)f2bf(v0.z) | ((unsigned)f2bf(v0.w) << 16);
    r.z = (unsigned)f2bf(v1.x) | ((unsigned)f2bf(v1.y) << 16);
    r.w = (unsigned)f2bf(v1.z) | ((unsigned)f2bf(v1.w) << 16);
    reinterpret_cast<uint4*>(d)[o] = r;
}

// ---------------------------------------------------------------------------
// W [k][n] f32 -> Wt [n][k] bf16 for the 4 weight matrices. 64 blocks.
// ---------------------------------------------------------------------------
__global__ __launch_bounds__(256) void prep_w_kernel(
    const float* __restrict__ Wa, const float* __restrict__ Wb,
    const float* __restrict__ Wc, const float* __restrict__ Wd,
    unsigned short* __restrict__ wt)
{
    const int wsel = blockIdx.x >> 4;
    const float* W = wsel == 0 ? Wa : wsel == 1 ? Wb : wsel == 2 ? Wc : Wd;
    unsigned short* out = wt + (size_t)wsel * D * D;
    const int tile = blockIdx.x & 15;
    const int k0 = (tile >> 2) * 32, n0 = (tile & 3) * 32;
    __shared__ float s[32][33];
    const int t = threadIdx.x;
    const int r = t >> 3, c = (t & 7) * 4;
    float4 v = *reinterpret_cast<const float4*>(W + (size_t)(k0 + r) * D + n0 + c);
    s[r][c] = v.x; s[r][c + 1] = v.y; s[r][c + 2] = v.z; s[r][c + 3] = v.w;
    __syncthreads();
    unsigned lo = (unsigned)f2bf(s[c][r]) | ((unsigned)f2bf(s[c + 1][r]) << 16);
    unsigned hi = (unsigned)f2bf(s[c + 2][r]) | ((unsigned)f2bf(s[c + 3][r]) << 16);
    *reinterpret_cast<uint2*>(out + (size_t)(n0 + r) * D + k0 + c) =
        make_uint2(lo, hi);
}

// ---------------------------------------------------------------------------
// CSR build step 1: histogram of dst; also records each edge's arrival rank
// within its dst segment (atomicAdd return) -> fill needs no atomics.
// ---------------------------------------------------------------------------
__global__ void hist_kernel(CsrRel r0, CsrRel r1)
{
    CsrRel r = blockIdx.y ? r1 : r0;
    int e = blockIdx.x * blockDim.x + threadIdx.x;
    if (e < r.E) r.rank[e] = atomicAdd(&r.counts[r.dst[e]], 1);
}

__global__ __launch_bounds__(256) void scan_partial_kernel(CsrRel rr0, CsrRel rr1)
{
    CsrRel r = blockIdx.y ? rr1 : rr0;
    if ((int)blockIdx.x >= r.nscan) return;
    __shared__ int red[256];
    const int t = threadIdx.x;
    const int base = blockIdx.x * 1024 + t * 4;
    int s = 0;
    if (base + 3 < r.N) {
        int4 q = *reinterpret_cast<const int4*>(r.counts + base);
        s = q.x + q.y + q.z + q.w;
    } else {
        for (int j = 0; j < 4; ++j)
            if (base + j < r.N) s += r.counts[base + j];
    }
    red[t] = s;
    __syncthreads();
    for (int off = 128; off > 0; off >>= 1) {
        if (t < off) red[t] += red[t + off];
        __syncthreads();
    }
    if (t == 0) r.bsum[blockIdx.x] = red[0];
}

__global__ __launch_bounds__(256) void scan_partials_kernel(CsrRel rr0, CsrRel rr1)
{
    CsrRel r = blockIdx.y ? rr1 : rr0;
    __shared__ int part[256];
    const int t = threadIdx.x;
    int v = (t < r.nscan) ? r.bsum[t] : 0;
    part[t] = v;
    __syncthreads();
    for (int off = 1; off < 256; off <<= 1) {
        int tmp = (t >= off) ? part[t - off] : 0;
        __syncthreads();
        part[t] += tmp;
        __syncthreads();
    }
    if (t < r.nscan) r.bsum[t] = part[t] - v;  // exclusive
}

__global__ __launch_bounds__(256) void scan_block_kernel(CsrRel rr0, CsrRel rr1)
{
    CsrRel r = blockIdx.y ? rr1 : rr0;
    if ((int)blockIdx.x >= r.nscan) return;
    __shared__ int part[256];
    const int b = blockIdx.x, t = threadIdx.x;
    const int base = b * 1024 + t * 4;
    int v[4] = {0, 0, 0, 0};
    if (base + 3 < r.N) {
        int4 q = *reinterpret_cast<const int4*>(r.counts + base);
        v[0] = q.x; v[1] = q.y; v[2] = q.z; v[3] = q.w;
    } else {
        for (int j = 0; j < 4; ++j)
            if (base + j < r.N) v[j] = r.counts[base + j];
    }
    int s = v[0] + v[1] + v[2] + v[3];
    part[t] = s;
    __syncthreads();
    for (int off = 1; off < 256; off <<= 1) {
        int tmp = (t >= off) ? part[t - off] : 0;
        __syncthreads();
        part[t] += tmp;
        __syncthreads();
    }
    int excl = part[t] - s + r.bsum[b];
    int o0 = excl, o1 = o0 + v[0], o2 = o1 + v[1], o3 = o2 + v[2];
    if (base + 3 < r.N) {
        *reinterpret_cast<int4*>(r.offsets + base) = make_int4(o0, o1, o2, o3);
    } else {
        int oo[4] = {o0, o1, o2, o3};
        for (int j = 0; j < 4; ++j)
            if (base + j < r.N) r.offsets[base + j] = oo[j];
    }
    if (b == r.nscan - 1 && t == 255) r.offsets[r.N] = r.bsum[b] + part[255];
}

// ---------------------------------------------------------------------------
// CSR build step 3: perm[offsets[d] + rank[e]] = src[e].  No atomics.
// Dst-bucketed for write locality: 8 bucket-blocks per edge chunk; bucket b
// handles edges whose dst lies in the b-th eighth of the node range, so each
// bucket's perm writes stay in a private ~E/8 window (L2-resident lines get
// many 4B hits before writeback instead of one).
// ---------------------------------------------------------------------------
#define FILL_EPT 8   // edges scanned per thread per chunk
__global__ __launch_bounds__(256) void fill_kernel(CsrRel rr0, CsrRel rr1)
{
    CsrRel r = blockIdx.y ? rr1 : rr0;
    const int bucket = blockIdx.x & 7;
    const int chunk = blockIdx.x >> 3;
    const int nper = (r.N + 7) >> 3;
    const int lo = bucket * nper, hi = lo + nper;
    const int base = chunk * (256 * FILL_EPT) + threadIdx.x;
#pragma unroll
    for (int k = 0; k < FILL_EPT; ++k) {
        int e = base + k * 256;
        if (e < r.E) {
            int d = r.dst[e];
            if (d >= lo && d < hi)
                r.perm[r.offsets[d] + r.rank[e]] = r.src[e];
        }
    }
}

// ---------------------------------------------------------------------------
// Gather-aggregate from bf16 table: x[row] = h_dst[row](f32) + sum h_src[perm].
// One wave per row, 2 cols per lane, f32 accumulation, bf16 output.
// ---------------------------------------------------------------------------
__global__ __launch_bounds__(256) void gather_agg_kernel(GatherRel g0, GatherRel g1)
{
    GatherRel g = blockIdx.y ? g1 : g0;
    int row = blockIdx.x * 4 + (threadIdx.x >> 6);
    row = __builtin_amdgcn_readfirstlane(row);
    if (row >= g.N) return;
    const int c = (threadIdx.x & 63) * 2;
    const int beg = g.offsets[row], end = g.offsets[row + 1];
    float2 acc = *reinterpret_cast<const float2*>(g.hdst + (size_t)row * D + c);
    const unsigned short* hb = g.hb;
    int i = beg;
    for (; i + 3 < end; i += 4) {
        int s0 = g.perm[i], s1 = g.perm[i + 1];
        int s2 = g.perm[i + 2], s3 = g.perm[i + 3];
        unsigned u0 = *reinterpret_cast<const unsigned*>(hb + (size_t)s0 * D + c);
        unsigned u1 = *reinterpret_cast<const unsigned*>(hb + (size_t)s1 * D + c);
        unsigned u2 = *reinterpret_cast<const unsigned*>(hb + (size_t)s2 * D + c);
        unsigned u3 = *reinterpret_cast<const unsigned*>(hb + (size_t)s3 * D + c);
        acc.x += (bflo(u0) + bflo(u1)) + (bflo(u2) + bflo(u3));
        acc.y += (bfhi(u0) + bfhi(u1)) + (bfhi(u2) + bfhi(u3));
    }
    for (; i < end; ++i) {
        unsigned u = *reinterpret_cast<const unsigned*>(hb + (size_t)g.perm[i] * D + c);
        acc.x += bflo(u);
        acc.y += bfhi(u);
    }
    unsigned o = (unsigned)f2bf(acc.x) | ((unsigned)f2bf(acc.y) << 16);
    *reinterpret_cast<unsigned*>(g.x + (size_t)row * D + c) = o;
}

// ---------------------------------------------------------------------------
// bn+relu applied to bf16 u32 pair (2 elems), repacked to bf16.
// ---------------------------------------------------------------------------
__device__ __forceinline__ unsigned bnpack(unsigned u, float sLo, float sHi,
                                           float bLo, float bHi)
{
    float lo = fmaxf(fmaf(bflo(u), sLo, bLo), 0.f);
    float hi = fmaxf(fmaf(bfhi(u), sHi, bHi), 0.f);
    return (unsigned)f2bf(lo) | ((unsigned)f2bf(hi) << 16);
}

// ---------------------------------------------------------------------------
// MFMA GEMM: Y(bf16) = X(bf16) @ W, W as Wt[n][k] bf16 preloaded into VGPRs.
// If BN_IN: per-block prologue computes scale/bias from (insum,insq,g,b) into
// LDS (replaces a separate bn_finalize launch), applied to A on load.
// Per-column sum/sumsq of Y accumulate in registers; one atomic set per block.
// ---------------------------------------------------------------------------
template <bool BN_IN>
__global__ __launch_bounds__(256, 2) void gemm_stats_kernel(GemmRel q0, GemmRel q1)
{
    GemmRel q = blockIdx.y ? q1 : q0;
    const int t = threadIdx.x;
    const int w = t >> 6;
    const int l = t & 63;
    const int lr = l & 15;          // A row / D col within fragment
    const int lk = (l >> 4) << 3;   // k offset within 32-step

    __shared__ float s_sc[D], s_bi[D];
    if constexpr (BN_IN) {
        if (t < D) {
            float inv_n = 1.f / (float)q.N;
            float mean = q.insum[t] * inv_n;
            float var = fmaxf(q.insq[t] * inv_n - mean * mean, 0.f);
            float s = q.gg[t] * rsqrtf(var + BN_EPS);
            s_sc[t] = s;
            s_bi[t] = q.bb[t] - mean * s;
        }
        __syncthreads();
    }

    // Preload all W fragments: frag(kk, n) = Wt[n*16+lr][kk*32+lk .. +8]
    uint4 wf[4][8];
#pragma unroll
    for (int kk = 0; kk < 4; ++kk)
#pragma unroll
        for (int n = 0; n < 8; ++n)
            wf[kk][n] = *reinterpret_cast<const uint4*>(
                q.Wt + (size_t)(n * 16 + lr) * D + kk * 32 + lk);

    float ps[8], pq[8];
#pragma unroll
    for (int n = 0; n < 8; ++n) { ps[n] = 0.f; pq[n] = 0.f; }

    for (int tile = blockIdx.x; tile < q.ntiles; tile += gridDim.x) {
        const int arow = tile * 64 + w * 16 + lr;
        f32x4 acc[8];
#pragma unroll
        for (int n = 0; n < 8; ++n) acc[n] = (f32x4){0.f, 0.f, 0.f, 0.f};

#pragma unroll
        for (int kk = 0; kk < 4; ++kk) {
            uint4 a4 = make_uint4(0u, 0u, 0u, 0u);
            if (arow < q.N) {
                a4 = *reinterpret_cast<const uint4*>(
                    q.X + (size_t)arow * D + kk * 32 + lk);
                if constexpr (BN_IN) {
                    const int kb = kk * 32 + lk;
                    float4 s0 = *reinterpret_cast<const float4*>(&s_sc[kb]);
                    float4 s1 = *reinterpret_cast<const float4*>(&s_sc[kb + 4]);
                    float4 b0 = *reinterpret_cast<const float4*>(&s_bi[kb]);
                    float4 b1 = *reinterpret_cast<const float4*>(&s_bi[kb + 4]);
                    a4.x = bnpack(a4.x, s0.x, s0.y, b0.x, b0.y);
                    a4.y = bnpack(a4.y, s0.z, s0.w, b0.z, b0.w);
                    a4.z = bnpack(a4.z, s1.x, s1.y, b1.x, b1.y);
                    a4.w = bnpack(a4.w, s1.z, s1.w, b1.z, b1.w);
                }
            }
            short8 a = __builtin_bit_cast(short8, a4);
#pragma unroll
            for (int n = 0; n < 8; ++n)
                acc[n] = __builtin_amdgcn_mfma_f32_16x16x32_bf16(
                    a, __builtin_bit_cast(short8, wf[kk][n]), acc[n], 0, 0, 0);
        }

        const int orow = tile * 64 + w * 16 + (l >> 4) * 4;
#pragma unroll
        for (int n = 0; n < 8; ++n) {
#pragma unroll
            for (int j = 0; j < 4; ++j) {
                float v = acc[n][j];
                ps[n] += v;          // pad rows produce exact 0 (A row zeroed)
                pq[n] += v * v;
                if (orow + j < q.N)
                    q.Y[(size_t)(orow + j) * D + n * 16 + lr] = f2bf(v);
            }
        }
    }

    // Cross-lane: reduce over the 4 row-groups (lanes l, l^16, l^32).
#pragma unroll
    for (int n = 0; n < 8; ++n) {
        ps[n] += __shfl_xor(ps[n], 16); ps[n] += __shfl_xor(ps[n], 32);
        pq[n] += __shfl_xor(pq[n], 16); pq[n] += __shfl_xor(pq[n], 32);
    }
    __shared__ float ssum[4][D], ssq[4][D];
    if (l < 16) {
#pragma unroll
        for (int n = 0; n < 8; ++n) {
            ssum[w][n * 16 + l] = ps[n];
            ssq[w][n * 16 + l]  = pq[n];
        }
    }
    __syncthreads();
    if (t < D) {
        float a = ssum[0][t] + ssum[1][t] + ssum[2][t] + ssum[3][t];
        float b = ssq[0][t] + ssq[1][t] + ssq[2][t] + ssq[3][t];
        atomicAdd(&q.osum[t], a);
        atomicAdd(&q.osq[t], b);
    }
}

// ---------------------------------------------------------------------------
// out(f32) = relu(bn(z bf16)); BN finalize computed per block from raw sums.
// ---------------------------------------------------------------------------
__global__ __launch_bounds__(256) void bn_relu_out_kernel(OutRel o0, OutRel o1)
{
    OutRel o = blockIdx.y ? o1 : o0;
    __shared__ float s_sc[D], s_bi[D];
    if (threadIdx.x < D) {
        int c = threadIdx.x;
        float inv_n = 1.f / (float)o.N;
        float mean = o.sum[c] * inv_n;
        float var = fmaxf(o.sq[c] * inv_n - mean * mean, 0.f);
        float s = o.gg[c] * rsqrtf(var + BN_EPS);
        s_sc[c] = s;
        s_bi[c] = o.bb[c] - mean * s;
    }
    __syncthreads();

    const int n8 = o.N * (D / 8);
    for (int i = blockIdx.x * blockDim.x + threadIdx.x; i < n8;
         i += gridDim.x * blockDim.x) {
        uint4 z = reinterpret_cast<const uint4*>(o.z)[i];
        int c = (i * 8) & (D - 1);
        float4 s0 = *reinterpret_cast<const float4*>(&s_sc[c]);
        float4 s1 = *reinterpret_cast<const float4*>(&s_sc[c + 4]);
        float4 b0 = *reinterpret_cast<const float4*>(&s_bi[c]);
        float4 b1 = *reinterpret_cast<const float4*>(&s_bi[c + 4]);
        float4 r0, r1;
        r0.x = fmaxf(fmaf(bflo(z.x), s0.x, b0.x), 0.f);
        r0.y = fmaxf(fmaf(bfhi(z.x), s0.y, b0.y), 0.f);
        r0.z = fmaxf(fmaf(bflo(z.y), s0.z, b0.z), 0.f);
        r0.w = fmaxf(fmaf(bfhi(z.y), s0.w, b0.w), 0.f);
        r1.x = fmaxf(fmaf(bflo(z.z), s1.x, b1.x), 0.f);
        r1.y = fmaxf(fmaf(bfhi(z.z), s1.y, b1.y), 0.f);
        r1.z = fmaxf(fmaf(bflo(z.w), s1.z, b1.z), 0.f);
        r1.w = fmaxf(fmaf(bfhi(z.w), s1.w, b1.w), 0.f);
        reinterpret_cast<float4*>(o.out)[i * 2] = r0;
        reinterpret_cast<float4*>(o.out)[i * 2 + 1] = r1;
    }
}

// ---------------------------------------------------------------------------
extern "C" void kernel_launch(void* const* d_in, const int* in_sizes, int n_in,
                              void* d_out, int out_size, void* d_ws, size_t ws_size,
                              hipStream_t stream)
{
    const float* h_user   = (const float*)d_in[0];
    const float* h_item   = (const float*)d_in[1];
    const int* src_rates  = (const int*)d_in[2];
    const int* dst_rates  = (const int*)d_in[3];
    const int* src_rev    = (const int*)d_in[4];
    const int* dst_rev    = (const int*)d_in[5];
    const float* W1_rates = (const float*)d_in[6];
    const float* W2_rates = (const float*)d_in[7];
    const float* g1_rates = (const float*)d_in[8];
    const float* b1_rates = (const float*)d_in[9];
    const float* g2_rates = (const float*)d_in[10];
    const float* b2_rates = (const float*)d_in[11];
    const float* W1_rev   = (const float*)d_in[12];
    const float* W2_rev   = (const float*)d_in[13];
    const float* g1_rev   = (const float*)d_in[14];
    const float* b1_rev   = (const float*)d_in[15];
    const float* g2_rev   = (const float*)d_in[16];
    const float* b2_rev   = (const float*)d_in[17];

    const int n_user = in_sizes[0] / D;
    const int n_item = in_sizes[1] / D;
    const int E1 = in_sizes[2];
    const int E2 = in_sizes[4];

    // Workspace layout (256-aligned slices); zero-region = [stats .. counts1).
    char* p = (char*)d_ws;
    auto alloc = [&](size_t bytes) {
        char* q = p;
        p += (bytes + 255) & ~(size_t)255;
        return q;
    };
    unsigned short* hbu = (unsigned short*)alloc((size_t)n_user * D * 2);
    unsigned short* hbi = (unsigned short*)alloc((size_t)n_item * D * 2);
    unsigned short* xz0 = (unsigned short*)alloc((size_t)n_item * D * 2);
    unsigned short* xz1 = (unsigned short*)alloc((size_t)n_user * D * 2);
    unsigned short* yb0 = (unsigned short*)alloc((size_t)n_item * D * 2);
    unsigned short* yb1 = (unsigned short*)alloc((size_t)n_user * D * 2);
    unsigned short* wt  = (unsigned short*)alloc((size_t)4 * D * D * 2);
    char* zbeg = p;
    float* stats   = (float*)alloc((size_t)8 * D * 4);   // 2 rel x 4 arrays x D
    int* counts0   = (int*)alloc((size_t)n_item * 4);
    int* counts1   = (int*)alloc((size_t)n_user * 4);
    size_t zbytes  = (size_t)(p - zbeg);
    int* offsets0  = (int*)alloc(((size_t)n_item + 1) * 4);
    int* offsets1  = (int*)alloc(((size_t)n_user + 1) * 4);
    int* bsum0     = (int*)alloc((size_t)256 * 4);
    int* bsum1     = (int*)alloc((size_t)256 * 4);
    int* perm0     = (int*)alloc((size_t)E1 * 4);
    int* perm1     = (int*)alloc((size_t)E2 * 4);
    int* rank0     = (int*)alloc((size_t)E1 * 4);
    int* rank1     = (int*)alloc((size_t)E2 * 4);

    float* out_user = (float*)d_out;
    float* out_item = out_user + (size_t)n_user * D;

    // Upfront: bf16 tables, transposed bf16 weights, zero stats+counts.
    const int nu8 = n_user * D / 8, ni8 = n_item * D / 8;
    convert_h_kernel<<<(nu8 + ni8 + 255) / 256, 256, 0, stream>>>(
        h_user, h_item, hbu, hbi, nu8, ni8);
    prep_w_kernel<<<64, 256, 0, stream>>>(W1_rates, W2_rates, W1_rev, W2_rev, wt);
    hipMemsetAsync(zbeg, 0, zbytes, stream);

    // Per-relation stat slices: [sum1, sq1, sum2, sq2] x D
    float* st0 = stats;
    float* st1 = stats + 4 * D;

    // rel0 ('rates'): user -> item, out_item. rel1 ('rated_by'): item -> user.
    CsrRel c0 = {src_rates, dst_rates, counts0, offsets0, bsum0, perm0, rank0,
                 E1, n_item, (n_item + 1023) / 1024};
    CsrRel c1 = {src_rev, dst_rev, counts1, offsets1, bsum1, perm1, rank1,
                 E2, n_user, (n_user + 1023) / 1024};

    int emax = E1 > E2 ? E1 : E2;
    int eb = (emax + 255) / 256;
    int ns = c0.nscan > c1.nscan ? c0.nscan : c1.nscan;
    hist_kernel<<<dim3(eb, 2), 256, 0, stream>>>(c0, c1);
    scan_partial_kernel<<<dim3(ns, 2), 256, 0, stream>>>(c0, c1);
    scan_partials_kernel<<<dim3(1, 2), 256, 0, stream>>>(c0, c1);
    scan_block_kernel<<<dim3(ns, 2), 256, 0, stream>>>(c0, c1);
    int fb = 8 * ((emax + 256 * FILL_EPT - 1) / (256 * FILL_EPT));
    fill_kernel<<<dim3(fb, 2), 256, 0, stream>>>(c0, c1);

    GatherRel ga0 = {hbu, h_item, offsets0, perm0, xz0, n_item};
    GatherRel ga1 = {hbi, h_user, offsets1, perm1, xz1, n_user};
    int ab = ((n_item > n_user ? n_item : n_user) + 3) / 4;
    gather_agg_kernel<<<dim3(ab, 2), 256, 0, stream>>>(ga0, ga1);

    const int nt0 = (n_item + 63) / 64, nt1 = (n_user + 63) / 64;
    int gx = nt0 > nt1 ? nt0 : nt1;
    if (gx > 256) gx = 256;   // 512 total blocks = 2/CU capacity

    // GEMM1: y = x @ W1, stats of y.
    GemmRel q10 = {xz0, wt,             nullptr, nullptr, nullptr, nullptr,
                   yb0, st0, st0 + D, n_item, nt0};
    GemmRel q11 = {xz1, wt + 2 * D * D, nullptr, nullptr, nullptr, nullptr,
                   yb1, st1, st1 + D, n_user, nt1};
    gemm_stats_kernel<false><<<dim3(gx, 2), 256, 0, stream>>>(q10, q11);

    // GEMM2: z = relu(bn1(y)) @ W2 (bn1 finalized in-kernel), stats of z.
    GemmRel q20 = {yb0, wt + D * D,     st0, st0 + D, g1_rates, b1_rates,
                   xz0, st0 + 2 * D, st0 + 3 * D, n_item, nt0};
    GemmRel q21 = {yb1, wt + 3 * D * D, st1, st1 + D, g1_rev, b1_rev,
                   xz1, st1 + 2 * D, st1 + 3 * D, n_user, nt1};
    gemm_stats_kernel<true><<<dim3(gx, 2), 256, 0, stream>>>(q20, q21);

    // out = relu(bn2(z)) (bn2 finalized in-kernel).
    OutRel o0 = {xz0, st0 + 2 * D, st0 + 3 * D, g2_rates, b2_rates,
                 out_item, n_item};
    OutRel o1 = {xz1, st1 + 2 * D, st1 + 3 * D, g2_rev, b2_rev,
                 out_user, n_user};
    int n8m = (n_item > n_user ? n_item : n_user) * (D / 8);
    int ob = (n8m + 255) / 256;
    if (ob > 2048) ob = 2048;
    bn_relu_out_kernel<<<dim3(ob, 2), 256, 0, stream>>>(o0, o1);
}